// Round 11
// baseline (196.772 us; speedup 1.0000x reference)
//
#include <hip/hip_runtime.h>
#include <stdint.h>

#define NN 50000
#define NE 800000
#define NG 64
#define F1 256
#define NNP 50176    // padded node count: 392*128, multiple of 448 and 512
#define NBK 196      // dst buckets (d >> 8), 196*256 >= 50000
#define NBS 392      // src buckets (s >> 7), 392*128 = 50176 >= 50000
#define EPB 2048     // edges per k_bscatter block
#define SCB 391      // ceil(NE / EPB)
#define PCHUNKS 112  // k_poolmm K-chunks (112*448 = 50176 exactly)
#define PKC 448      // K per chunk = 7 * 64
#define PSTEPS 7     // BK=64 steps per chunk
#define ZR2 128      // zpart rows per chunk: 64 z-partial (hi+lo folded) + 64 ind

typedef __bf16 bf16x8 __attribute__((ext_vector_type(8)));
typedef float f32x4 __attribute__((ext_vector_type(4)));
typedef float f32x2 __attribute__((ext_vector_type(2)));

__device__ __forceinline__ float bf2f(unsigned int u) {
  union { float f; unsigned int i; } v; v.i = (u & 0xffffu) << 16; return v.f;
}
__device__ __forceinline__ unsigned short f2bf(float f) {
  union { float f; unsigned int i; } v; v.f = f;
  unsigned int r = v.i + 0x7fffu + ((v.i >> 16) & 1u);
  return (unsigned short)(r >> 16);
}
__device__ __forceinline__ float asf(unsigned int u) {
  union { unsigned int u; float f; } v; v.u = u; return v.f;
}
__device__ __forceinline__ unsigned int asu(float f) {
  union { float f; unsigned int u; } v; v.f = f; return v.u;
}
// global->LDS DMA, 16B/lane. LDS dest is wave-uniform base + lane*16 (linear);
// swizzles must be applied on the per-lane GLOBAL source address (rule #21).
__device__ __forceinline__ void gload16(const void* g, void* l) {
  __builtin_amdgcn_global_load_lds(
      (const __attribute__((address_space(1))) unsigned int*)g,
      (__attribute__((address_space(3))) unsigned int*)l, 16, 0, 0);
}
// CDNA dual-FP32 FMA (v_pk_fma_f32, VOP3P). op_sel/op_sel_hi broadcast one
// 32-bit word of src0 to BOTH result lanes — lets the (a0,x) edge pair feed
// both features without any v_mov. Bit-identical to scalar fmaf (IEEE fused).
__device__ __forceinline__ f32x2 pkfma_lo(f32x2 s, f32x2 b, f32x2 c) {
  f32x2 d;  // d.i = s.LO * b.i + c.i
  asm("v_pk_fma_f32 %0, %1, %2, %3 op_sel_hi:[0,1,1]"
      : "=v"(d) : "v"(s), "v"(b), "v"(c));
  return d;
}
__device__ __forceinline__ f32x2 pkfma_hi(f32x2 s, f32x2 b, f32x2 c) {
  f32x2 d;  // d.i = s.HI * b.i + c.i
  asm("v_pk_fma_f32 %0, %1, %2, %3 op_sel:[1,0,0]"
      : "=v"(d) : "v"(s), "v"(b), "v"(c));
  return d;
}

// ---- K1: dual coarse histograms (dst>>8 and src>>7), LDS-merged ----
__global__ void k_bhist(const int* __restrict__ ei, int* __restrict__ btot_d,
                        int* __restrict__ btot_s) {
  __shared__ int lhd[NBK];
  __shared__ int lhs[NBS];
  for (int i = threadIdx.x; i < NBK; i += 256) lhd[i] = 0;
  for (int i = threadIdx.x; i < NBS; i += 256) lhs[i] = 0;
  __syncthreads();
  for (int e = blockIdx.x * blockDim.x + threadIdx.x; e < NE; e += gridDim.x * blockDim.x) {
    atomicAdd(&lhs[ei[e] >> 7], 1);
    atomicAdd(&lhd[ei[NE + e] >> 8], 1);
  }
  __syncthreads();
  for (int i = threadIdx.x; i < NBK; i += 256) atomicAdd(&btot_d[i], lhd[i]);
  for (int i = threadIdx.x; i < NBS; i += 256) atomicAdd(&btot_s[i], lhs[i]);
}

// ---- K2: scan both bucket-total arrays -> bases/cursors; rowp[NN]=NE ----
__global__ void k_bscan(const int* __restrict__ btot_d, const int* __restrict__ btot_s,
                        int* __restrict__ bbase, int* __restrict__ bcur,
                        int* __restrict__ sbase, int* __restrict__ scur,
                        int* __restrict__ rowp) {
  __shared__ int buf[512];
  int t = threadIdx.x;
  int v = (t < NBK) ? btot_d[t] : 0;
  buf[t] = v;
  __syncthreads();
  for (int off = 1; off < 512; off <<= 1) {
    int o = (t >= off) ? buf[t - off] : 0;
    __syncthreads();
    buf[t] += o;
    __syncthreads();
  }
  if (t < NBK) { bbase[t] = buf[t] - v; bcur[t] = buf[t] - v; }
  if (t == NBK - 1) bbase[NBK] = buf[t];
  __syncthreads();
  int v2 = (t < NBS) ? btot_s[t] : 0;
  buf[t] = v2;
  __syncthreads();
  for (int off = 1; off < 512; off <<= 1) {
    int o = (t >= off) ? buf[t - off] : 0;
    __syncthreads();
    buf[t] += o;
    __syncthreads();
  }
  if (t < NBS) { sbase[t] = buf[t] - v2; scur[t] = buf[t] - v2; }
  if (t == NBS - 1) sbase[NBS] = buf[t];
  if (t == 0) rowp[NN] = NE;
}

// ---- K3: dual scatter: dst-records {s|d<<16, x[s]} and src-records {d|sl<<16} ----
__global__ __launch_bounds__(256) void k_bscatter(
    const int* __restrict__ ei, const float* __restrict__ x,
    int* __restrict__ bcur, int* __restrict__ scur,
    uint2* __restrict__ recs, unsigned int* __restrict__ srecs) {
  __shared__ int lhd[NBK]; __shared__ int gbd[NBK];
  __shared__ int lhs[NBS]; __shared__ int gbs[NBS];
  int b = blockIdx.x, tid = threadIdx.x;
  int e0 = b * EPB;
  for (int i = tid; i < NBK; i += 256) lhd[i] = 0;
  for (int i = tid; i < NBS; i += 256) lhs[i] = 0;
  __syncthreads();
  unsigned int meta[8]; float xv[8]; int lofd[8]; int bkd[8]; int lofs[8]; int bks[8];
#pragma unroll
  for (int i = 0; i < 8; ++i) {
    int e = e0 + i * 256 + tid;
    bkd[i] = -1;
    if (e < NE) {
      int s = ei[e], d = ei[NE + e];
      bkd[i] = d >> 8; bks[i] = s >> 7;
      meta[i] = (unsigned int)s | ((unsigned int)d << 16);  // s,d < 65536
      xv[i] = x[s];
      lofd[i] = atomicAdd(&lhd[bkd[i]], 1);
      lofs[i] = atomicAdd(&lhs[bks[i]], 1);
    }
  }
  __syncthreads();
  for (int i = tid; i < NBK; i += 256) gbd[i] = atomicAdd(&bcur[i], lhd[i]);
  for (int i = tid; i < NBS; i += 256) gbs[i] = atomicAdd(&scur[i], lhs[i]);
  __syncthreads();
#pragma unroll
  for (int i = 0; i < 8; ++i) {
    if (bkd[i] >= 0) {
      recs[gbd[bkd[i]] + lofd[i]] = make_uint2(meta[i], asu(xv[i]));
      unsigned int s = meta[i] & 0xFFFFu, d = meta[i] >> 16;
      srecs[gbs[bks[i]] + lofs[i]] = d | ((s & 127u) << 16);
    }
  }
}

// ---- K4: per-dst-bucket fine CSR + per-node ax + dg table + colx scatter ----
__global__ __launch_bounds__(256) void k_csr(
    const uint2* __restrict__ recs, const int* __restrict__ bbase,
    const float* __restrict__ x, const int* __restrict__ batch,
    int* __restrict__ rowp, float2* __restrict__ ax,
    int* __restrict__ colx, uint2* __restrict__ dg) {
  __shared__ int cnt[256];
  __shared__ int sc[256];
  __shared__ float xs[256];
  int b = blockIdx.x, tid = threadIdx.x;
  int eb = bbase[b], ee = bbase[b + 1];
  cnt[tid] = 0;
  xs[tid] = 0.0f;
  __syncthreads();
  for (int e = eb + tid; e < ee; e += 256) {
    uint2 r = recs[e];
    int dl = (r.x >> 16) & 255;
    atomicAdd(&cnt[dl], 1);
    atomicAdd(&xs[dl], asf(r.y));
  }
  __syncthreads();
  sc[tid] = cnt[tid];
  __syncthreads();
  for (int off = 1; off < 256; off <<= 1) {
    int o = (tid >= off) ? sc[tid - off] : 0;
    __syncthreads();
    sc[tid] += o;
    __syncthreads();
  }
  int excl = sc[tid] - cnt[tid];
  int i = b * 256 + tid;
  float dinv = 1.0f / fmaxf((float)cnt[tid], 1.0f);
  if (i < NN) {
    rowp[i] = eb + excl;
    ax[i] = make_float2(xs[tid] * dinv, x[i]);
    dg[i] = make_uint2(asu(dinv), (unsigned int)batch[i]);
  }
  __syncthreads();
  sc[tid] = excl;  // cursor
  __syncthreads();
  for (int e = eb + tid; e < ee; e += 256) {
    uint2 r = recs[e];
    int dl = (r.x >> 16) & 255;
    int s = r.x & 0xFFFF;
    int slot = atomicAdd(&sc[dl], 1);
    colx[eb + slot] = s;
  }
}

// ---- K5: per-src-bucket wg rows in LDS; emit TRANSPOSED bf16 wgT3 ----
// wgT3[g'][s]: rows 0..63 = bf16(wg) (hi), 64..127 = bf16(wg - hi) (lo),
// 128..191 = indicator bf16(batch[s]==g ? 1 : 0). Pad cols (s>=NN): all 0.
__global__ __launch_bounds__(256) void k_csc(
    const unsigned int* __restrict__ srecs, const int* __restrict__ sbase,
    const uint2* __restrict__ dg, const int* __restrict__ batch,
    unsigned int* __restrict__ wgT3u) {
  __shared__ float wgrow[128 * 65];  // [sl][g], pad 65 to break readout conflicts
  __shared__ int sbt[128];
  int b = blockIdx.x, tid = threadIdx.x;
  for (int i = tid; i < 128 * 65; i += 256) wgrow[i] = 0.0f;
  if (tid < 128) {
    int s = b * 128 + tid;
    sbt[tid] = (s < NN) ? batch[s] : -1;
  }
  __syncthreads();
  int eb = sbase[b], ee = sbase[b + 1];
  for (int e = eb + tid; e < ee; e += 256) {
    unsigned int r = srecs[e];
    int d = r & 0xFFFF;
    int sl = (r >> 16) & 127;
    uint2 t = dg[d];  // {deginv bits, g} — 400KB table, L2-resident
    atomicAdd(&wgrow[sl * 65 + t.y], asf(t.x));
  }
  __syncthreads();
  int s0u = b * 64;  // u32 column base (= b*128 bf16 cols / 2)
  int k = tid & 63;
  for (int rr = 0; rr < 16; ++rr) {
    int g = rr * 4 + (tid >> 6);
    float w0 = wgrow[(2 * k) * 65 + g];
    float w1 = wgrow[(2 * k + 1) * 65 + g];
    unsigned short h0 = f2bf(w0), h1v = f2bf(w1);
    unsigned short l0 = f2bf(w0 - bf2f(h0)), l1 = f2bf(w1 - bf2f(h1v));
    wgT3u[(size_t)g * (NNP / 2) + s0u + k] = (unsigned int)h0 | ((unsigned int)h1v << 16);
    wgT3u[(size_t)(64 + g) * (NNP / 2) + s0u + k] = (unsigned int)l0 | ((unsigned int)l1 << 16);
  }
  int bv0 = sbt[2 * k], bv1 = sbt[2 * k + 1];
  for (int rr = 0; rr < 16; ++rr) {
    int g = rr * 4 + (tid >> 6);
    unsigned int u = ((bv0 == g) ? 0x3F80u : 0u) | ((bv1 == g) ? 0x3F800000u : 0u);
    wgT3u[(size_t)(128 + g) * (NNP / 2) + s0u + k] = u;
  }
}

// ---- per-graph node count via binary search over sorted batch ----
__global__ void k_cnt(const int* __restrict__ batch, int* __restrict__ cnt) {
  int g = threadIdx.x;
  if (g >= NG) return;
  int lo = 0, hi = NN;
  while (lo < hi) { int m = (lo + hi) >> 1; if (batch[m] < g) lo = m + 1; else hi = m; }
  int a = lo;
  lo = 0; hi = NN;
  while (lo < hi) { int m = (lo + hi) >> 1; if (batch[m] < g + 1) lo = m + 1; else hi = m; }
  cnt[g] = lo - a;
}

// ---- materialize edge-ordered (a0,x): coalesced write, small-table gather ----
// ax is 400KB L2-resident; decoupling this gather from agg2's compute is the
// R7-proven structure (R8/R9 fused-gather variants: 45.7/51.2us vs ~36 split).
__global__ void k_axe(const int* __restrict__ colx, const float2* __restrict__ ax,
                      float2* __restrict__ axe) {
  int e = blockIdx.x * blockDim.x + threadIdx.x;
  if (e >= NE) return;
  axe[e] = ax[colx[e]];
}

// ---- wcat[n][k]: k<256 -> Wl1[k][n], else Wr1[k-256][n] ----
__global__ void k_wprep(const float* __restrict__ Wl1, const float* __restrict__ Wr1,
                        unsigned short* __restrict__ wcat) {
  int t = blockIdx.x * blockDim.x + threadIdx.x;
  if (t >= 256 * 512) return;
  int n = t >> 9, k = t & 511;
  float v = (k < 256) ? Wl1[k * 256 + n] : Wr1[(k - 256) * 256 + n];
  wcat[t] = f2bf(v);
}

// ---- layer-1 mean-aggregation: stream axe, packed-FP32 inner loop ----
// R8/R9 PMC: VALU-issue-bound (VALUBusy ~60%, HBM 8%). v_pk_fma_f32 with
// op_sel broadcast of the (a0,x) pair halves computes 2 features per instr
// with zero extra movs: 16 -> 12 ALU instr/edge, bit-identical results
// (pk_fma is IEEE fused; relu+accumulate stay scalar — no v_pk_max_f32).
__global__ __launch_bounds__(256) void k_agg2(
    const float2* __restrict__ axe, const int* __restrict__ rowp,
    const float* __restrict__ Wl0, const float* __restrict__ b0,
    const float* __restrict__ Wr0, unsigned short* __restrict__ aggb) {
  int wid = threadIdx.x >> 6, lane = threadIdx.x & 63;
  int gw = blockIdx.x * 4 + wid;
  int tw = gridDim.x * 4;
  f32x2 wl01 = *(const f32x2*)&Wl0[lane * 4];
  f32x2 wl23 = *(const f32x2*)&Wl0[lane * 4 + 2];
  f32x2 wr01 = *(const f32x2*)&Wr0[lane * 4];
  f32x2 wr23 = *(const f32x2*)&Wr0[lane * 4 + 2];
  f32x2 bb01 = *(const f32x2*)&b0[lane * 4];
  f32x2 bb23 = *(const f32x2*)&b0[lane * 4 + 2];
  for (int d = gw; d < NN; d += tw) {
    int beg = rowp[d], end = rowp[d + 1];
    f32x2 a01 = {0.f, 0.f}, a23 = {0.f, 0.f};
    f32x2 c01 = {0.f, 0.f}, c23 = {0.f, 0.f};
    int e = beg;
    for (; e + 3 < end; e += 4) {
      f32x2 v0 = *(const f32x2*)&axe[e];
      f32x2 v1 = *(const f32x2*)&axe[e + 1];
      f32x2 v2 = *(const f32x2*)&axe[e + 2];
      f32x2 v3 = *(const f32x2*)&axe[e + 3];
      f32x2 t;
      t = pkfma_lo(v0, wl01, pkfma_hi(v0, wr01, bb01));
      a01.x += fmaxf(t.x, 0.f); a01.y += fmaxf(t.y, 0.f);
      t = pkfma_lo(v0, wl23, pkfma_hi(v0, wr23, bb23));
      a23.x += fmaxf(t.x, 0.f); a23.y += fmaxf(t.y, 0.f);
      t = pkfma_lo(v1, wl01, pkfma_hi(v1, wr01, bb01));
      c01.x += fmaxf(t.x, 0.f); c01.y += fmaxf(t.y, 0.f);
      t = pkfma_lo(v1, wl23, pkfma_hi(v1, wr23, bb23));
      c23.x += fmaxf(t.x, 0.f); c23.y += fmaxf(t.y, 0.f);
      t = pkfma_lo(v2, wl01, pkfma_hi(v2, wr01, bb01));
      a01.x += fmaxf(t.x, 0.f); a01.y += fmaxf(t.y, 0.f);
      t = pkfma_lo(v2, wl23, pkfma_hi(v2, wr23, bb23));
      a23.x += fmaxf(t.x, 0.f); a23.y += fmaxf(t.y, 0.f);
      t = pkfma_lo(v3, wl01, pkfma_hi(v3, wr01, bb01));
      c01.x += fmaxf(t.x, 0.f); c01.y += fmaxf(t.y, 0.f);
      t = pkfma_lo(v3, wl23, pkfma_hi(v3, wr23, bb23));
      c23.x += fmaxf(t.x, 0.f); c23.y += fmaxf(t.y, 0.f);
    }
    for (; e < end; ++e) {
      f32x2 v0 = *(const f32x2*)&axe[e];
      f32x2 t;
      t = pkfma_lo(v0, wl01, pkfma_hi(v0, wr01, bb01));
      a01.x += fmaxf(t.x, 0.f); a01.y += fmaxf(t.y, 0.f);
      t = pkfma_lo(v0, wl23, pkfma_hi(v0, wr23, bb23));
      a23.x += fmaxf(t.x, 0.f); a23.y += fmaxf(t.y, 0.f);
    }
    float dinv = 1.0f / fmaxf((float)(end - beg), 1.0f);
    uint2 o;
    o.x = (unsigned int)f2bf((a01.x + c01.x) * dinv) |
          ((unsigned int)f2bf((a01.y + c01.y) * dinv) << 16);
    o.y = (unsigned int)f2bf((a23.x + c23.x) * dinv) |
          ((unsigned int)f2bf((a23.y + c23.y) * dinv) << 16);
    *(uint2*)(aggb + (size_t)d * F1 + lane * 4) = o;
  }
}

// ---- layer 1 GEMM v4: global_load_lds staged, single barrier per K-step ----
// A (kt<8, from aggb) and B (all kt, from wcat) staged via global_load_lds
// with pre-swizzled per-lane GLOBAL source (the R7-proven rule-#21 pattern);
// h0 half (kt>=8) computed in regs -> ds_write (overlaps DMA). aggb is padded
// to NNP rows (pad memset to 0) so DMA'd pad rows are finite; ax stays
// guarded. Epilogue: direct h1T[f][s] 8B stores (unswapped mfma orientation).
#define BM 128
#define BN 128
#define BK 32

__global__ __launch_bounds__(256) void k_gemm1(
    const unsigned short* __restrict__ aggb, const float2* __restrict__ ax,
    const unsigned short* __restrict__ wcat,
    const float* __restrict__ Wl0, const float* __restrict__ b0,
    const float* __restrict__ Wr0, const float* __restrict__ b1,
    unsigned short* __restrict__ h1T) {
  __shared__ unsigned short As[2][BM][BK];
  __shared__ unsigned short Bs[2][BN][BK];
  __shared__ float wl0s[256], wr0s[256], b0s[256];
  int bm = blockIdx.x, ct = blockIdx.y;
  int tid = threadIdx.x;
  int wid = tid >> 6, lane = tid & 63;
  int wr = wid >> 1, wc = wid & 1;
  int rc = lane & 15, kh = lane >> 4;
  int r0 = bm * BM;
  int srow = tid >> 1;   // 0..127: one computed row per thread (h0 path)
  int sslot = tid & 1;   // which 32B half of the 64B k-row

  wl0s[tid] = Wl0[tid];
  wr0s[tid] = Wr0[tid];
  b0s[tid] = b0[tid];

  int rA = r0 + srow;
  bool rAok = rA < NN;
  float2 axv = rAok ? ax[rA] : make_float2(0.f, 0.f);

  // DMA sources: lane covers LDS 16B-slot sIdx = wid*128 + j*64 + lane.
  // row = sIdx>>2, phys-slot = sIdx&3; logical slot sl = phys ^ ((row>>1)&3)
  // (the same involution the ds_read side uses) baked into the global addr.
  const unsigned short* gsa[2];
  const unsigned short* gsb[2];
  int ldst[2];
#pragma unroll
  for (int j = 0; j < 2; ++j) {
    int sIdx = wid * 128 + j * 64 + lane;
    int row = sIdx >> 2, phys = sIdx & 3;
    int sl = phys ^ ((row >> 1) & 3);
    gsa[j] = aggb + (size_t)(r0 + row) * F1 + sl * 8;          // pad rows zeroed
    gsb[j] = wcat + (size_t)(ct * BN + row) * 512 + sl * 8;
    ldst[j] = (wid * 128 + j * 64) * 8;  // wave-uniform element offset
  }

  f32x4 acc[4][4] = {};  // acc[mf][nf]: rows (kh,j) <-> s, col rc <-> f

#define DMA_A(buf, kt)                                                         \
  do {                                                                         \
    gload16(gsa[0] + (kt) * 32, &As[buf][0][0] + ldst[0]);                     \
    gload16(gsa[1] + (kt) * 32, &As[buf][0][0] + ldst[1]);                     \
  } while (0)

#define DMA_B(buf, kt)                                                         \
  do {                                                                         \
    gload16(gsb[0] + (kt) * 32, &Bs[buf][0][0] + ldst[0]);                     \
    gload16(gsb[1] + (kt) * 32, &Bs[buf][0][0] + ldst[1]);                     \
  } while (0)

// h0[rA][j] = relu(ax.x*Wl0[j] + ax.y*Wr0[j] + b0[j]) -> swizzled ds_write
#define COMPW_A(buf, kt)                                                       \
  do {                                                                         \
    int j0_ = ((kt) - 8) * BK + sslot * 16;                                    \
    unsigned int w_[8];                                                        \
    _Pragma("unroll") for (int q = 0; q < 8; ++q) {                            \
      int j_ = j0_ + 2 * q;                                                    \
      float f0_ = fmaxf(fmaf(axv.x, wl0s[j_], fmaf(axv.y, wr0s[j_], b0s[j_])), 0.0f); \
      float f1_ = fmaxf(fmaf(axv.x, wl0s[j_ + 1], fmaf(axv.y, wr0s[j_ + 1], b0s[j_ + 1])), 0.0f); \
      w_[q] = (unsigned int)f2bf(f0_) | ((unsigned int)f2bf(f1_) << 16);       \
    }                                                                          \
    int sw_ = (srow >> 1) & 3;                                                 \
    *(int4*)&As[buf][srow][((2 * sslot) ^ sw_) * 8] = make_int4(w_[0], w_[1], w_[2], w_[3]); \
    *(int4*)&As[buf][srow][((2 * sslot + 1) ^ sw_) * 8] = make_int4(w_[4], w_[5], w_[6], w_[7]); \
  } while (0)

  DMA_A(0, 0);
  DMA_B(0, 0);
  __syncthreads();  // drains DMA: buf0 ready (also publishes wl0s/wr0s/b0s)
  int cur = 0;
  for (int kt = 0; kt < 16; ++kt) {
    if (kt < 15) {
      DMA_B(cur ^ 1, kt + 1);
      if (kt + 1 < 8) DMA_A(cur ^ 1, kt + 1);
      else COMPW_A(cur ^ 1, kt + 1);
    }
    bf16x8 af[4], bfr[4];
#pragma unroll
    for (int mf = 0; mf < 4; ++mf) {
      int row = wr * 64 + mf * 16 + rc;
      int sl = kh ^ ((row >> 1) & 3);
      af[mf] = *(const bf16x8*)&As[cur][row][sl * 8];
    }
#pragma unroll
    for (int nf = 0; nf < 4; ++nf) {
      int row = wc * 64 + nf * 16 + rc;
      int sl = kh ^ ((row >> 1) & 3);
      bfr[nf] = *(const bf16x8*)&Bs[cur][row][sl * 8];
    }
#pragma unroll
    for (int mf = 0; mf < 4; ++mf)
#pragma unroll
      for (int nf = 0; nf < 4; ++nf)
        acc[mf][nf] = __builtin_amdgcn_mfma_f32_16x16x32_bf16(af[mf], bfr[nf], acc[mf][nf], 0, 0, 0);
    __syncthreads();  // drains next-buf DMA + ds_writes; protects cur
    cur ^= 1;
  }
#undef DMA_A
#undef DMA_B
#undef COMPW_A

  // ---- epilogue: bias+relu, direct h1T[f][s] 8B stores ----
#pragma unroll
  for (int nf = 0; nf < 4; ++nf) {
    int f = ct * BN + wc * 64 + nf * 16 + rc;
    float bias = b1[f];
    size_t frow = (size_t)f * NNP;
#pragma unroll
    for (int mf = 0; mf < 4; ++mf) {
      int s0 = r0 + wr * 64 + mf * 16 + kh * 4;
      f32x4 a = acc[mf][nf];
      unsigned int lo = (unsigned int)f2bf(fmaxf(a[0] + bias, 0.0f)) |
                        ((unsigned int)f2bf(fmaxf(a[1] + bias, 0.0f)) << 16);
      unsigned int hi = (unsigned int)f2bf(fmaxf(a[2] + bias, 0.0f)) |
                        ((unsigned int)f2bf(fmaxf(a[3] + bias, 0.0f)) << 16);
      *(uint2*)(h1T + frow + s0) = make_uint2(lo, hi);
    }
  }
}

// ---- pool contraction: global_load_lds double-buffered MFMA streamer ----
// (R7 structure, unchanged — 189us round verified.)
__global__ __launch_bounds__(256, 2) void k_poolmm(
    const unsigned short* __restrict__ h1T, const unsigned short* __restrict__ wgT3,
    float* __restrict__ zpart) {
  __shared__ unsigned short SM[2][2048 * 8];  // 2 x 32KB: slots 0..1535 = A(192 rows), 1536..2047 = B(64 rows)
  int bid = blockIdx.x;
  int lbid = (bid & 7) * 56 + (bid >> 3);  // XCD-bucket: 4 f-slices of a chunk share an XCD
  int c = lbid >> 2, fs = lbid & 3;
  int tid = threadIdx.x;
  int w = tid >> 6, lane = tid & 63, rc = lane & 15, kh = lane >> 4;
  int kbase = c * PKC;
  int fbase = fs * 64;

  const unsigned short* gsrc[8];
#pragma unroll
  for (int r = 0; r < 8; ++r) {
    int sIdx = r * 256 + tid;
    if (sIdx < 1536) {
      int row = sIdx >> 3, sl = sIdx & 7;
      gsrc[r] = wgT3 + (size_t)row * NNP + kbase + (sl ^ (row & 7)) * 8;
    } else {
      int row = (sIdx - 1536) >> 3, sl = sIdx & 7;
      gsrc[r] = h1T + (size_t)(fbase + row) * NNP + kbase + (sl ^ (row & 7)) * 8;
    }
  }

  f32x4 acc[12] = {};

#define PSTAGE(buf, t)                                                         \
  do {                                                                         \
    _Pragma("unroll") for (int r = 0; r < 8; ++r)                              \
      gload16(gsrc[r] + (t) * 64, &SM[buf][(r * 256 + w * 64) * 8]);           \
  } while (0)

#define PCOMP(buf)                                                             \
  do {                                                                         \
    _Pragma("unroll") for (int ks = 0; ks < 2; ++ks) {                         \
      int brow = w * 16 + rc;                                                  \
      int bsl = (ks * 4 + kh) ^ (brow & 7);                                    \
      bf16x8 bf = *(const bf16x8*)&SM[buf][(1536 + brow * 8 + bsl) * 8];       \
      _Pragma("unroll") for (int mt = 0; mt < 12; ++mt) {                      \
        int arow = mt * 16 + rc;                                               \
        int asl = (ks * 4 + kh) ^ (arow & 7);                                  \
        bf16x8 af = *(const bf16x8*)&SM[buf][(arow * 8 + asl) * 8];            \
        acc[mt] = __builtin_amdgcn_mfma_f32_16x16x32_bf16(af, bf, acc[mt], 0, 0, 0); \
      }                                                                        \
    }                                                                          \
  } while (0)

  PSTAGE(0, 0);
  __syncthreads();
#pragma unroll
  for (int t = 0; t < PSTEPS; ++t) {
    int buf = t & 1;
    if (t + 1 < PSTEPS) PSTAGE(buf ^ 1, t + 1);
    PCOMP(buf);
    __syncthreads();
  }
#undef PSTAGE
#undef PCOMP

  float* zp = zpart + ((size_t)c * ZR2) * F1 + fbase + w * 16 + rc;
#pragma unroll
  for (int mt = 0; mt < 4; ++mt)
#pragma unroll
    for (int r = 0; r < 4; ++r)
      zp[(size_t)(mt * 16 + kh * 4 + r) * F1] = acc[mt][r] + acc[mt + 4][r];
#pragma unroll
  for (int mt = 8; mt < 12; ++mt)
#pragma unroll
    for (int r = 0; r < 4; ++r)
      zp[(size_t)((mt - 8) * 16 + 64 + kh * 4 + r) * F1] = acc[mt][r];
}

// ---- zpart reduction: z[g][f] = sum_c zrow, p1[g][f] = sum_c ind ----
__global__ void k_zred(const float* __restrict__ zpart, float* __restrict__ z,
                       float* __restrict__ p1) {
  int g = blockIdx.x, q = blockIdx.y, t = threadIdx.x;  // grid (64, 8)
  float a = 0.0f, b = 0.0f;
  for (int c = q * 14; c < q * 14 + 14; ++c) {
    const float* base = zpart + (size_t)c * ZR2 * F1;
    a += base[(size_t)g * F1 + t];
    b += base[(size_t)(64 + g) * F1 + t];
  }
  atomicAdd(&z[g * F1 + t], a);
  atomicAdd(&p1[g * F1 + t], b);
}

// ---- final: g = (Z/cnt)@Wl2 + b2 + (P/cnt)@Wr2, then LayerNorm ----
__global__ void k_final(const float* __restrict__ z, const float* __restrict__ p1,
                        const int* __restrict__ cnt,
                        const float* __restrict__ Wl2, const float* __restrict__ b2,
                        const float* __restrict__ Wr2, const float* __restrict__ gamma,
                        const float* __restrict__ beta, float* __restrict__ out) {
  __shared__ float s1[128], s2[128];
  int g = blockIdx.x, j = threadIdx.x;
  float invc = 1.0f / fmaxf((float)cnt[g], 1.0f);
  float acc = 0.0f;
  for (int k = 0; k < 256; ++k) {
    acc += z[g * 256 + k] * Wl2[k * 128 + j] + p1[g * 256 + k] * Wr2[k * 128 + j];
  }
  acc = acc * invc + b2[j];
  s1[j] = acc; s2[j] = acc * acc;
  __syncthreads();
  for (int off = 64; off > 0; off >>= 1) {
    if (j < off) { s1[j] += s1[j + off]; s2[j] += s2[j + off]; }
    __syncthreads();
  }
  float mu = s1[0] / 128.0f;
  float var = s2[0] / 128.0f - mu * mu;
  out[g * 128 + j] = (acc - mu) * rsqrtf(var + 1e-5f) * gamma[j] + beta[j];
}

extern "C" void kernel_launch(void* const* d_in, const int* in_sizes, int n_in,
                              void* d_out, int out_size, void* d_ws, size_t ws_size,
                              hipStream_t stream) {
  const float* x = (const float*)d_in[0];
  const int* ei = (const int*)d_in[1];
  const int* batch = (const int*)d_in[2];
  const float* Wl0 = (const float*)d_in[3];
  const float* b0 = (const float*)d_in[4];
  const float* Wr0 = (const float*)d_in[5];
  const float* Wl1 = (const float*)d_in[6];
  const float* b1 = (const float*)d_in[7];
  const float* Wr1 = (const float*)d_in[8];
  const float* Wl2 = (const float*)d_in[9];
  const float* b2 = (const float*)d_in[10];
  const float* Wr2 = (const float*)d_in[11];
  const float* gamma = (const float*)d_in[12];
  const float* beta = (const float*)d_in[13];
  float* out = (float*)d_out;

  char* p = (char*)d_ws;
  auto alloc = [&](size_t bytes) {
    char* r = p;
    p += (bytes + 511) & ~(size_t)511;
    return r;
  };
  unsigned short* h1T = (unsigned short*)alloc((size_t)F1 * NNP * 2);    // 25.7MB transposed h1
  unsigned short* aggb = (unsigned short*)alloc((size_t)NNP * F1 * 2);   // padded to NNP rows; hosts recs+srecs early
  int* colx = (int*)alloc((size_t)NE * 4);                               // 3.2MB
  float2* axe = (float2*)alloc((size_t)NE * 8);                          // 6.4MB edge-ordered (a0,x)
  int* rowp = (int*)alloc((size_t)(NN + 1) * 4);
  float2* ax = (float2*)alloc((size_t)NN * 8);
  uint2* dg = (uint2*)alloc((size_t)NN * 8);
  int* cnt = (int*)alloc((size_t)NG * 4);
  float* z = (float*)alloc((size_t)NG * F1 * 4);
  float* p1 = (float*)alloc((size_t)NG * F1 * 4);
  unsigned short* wcat = (unsigned short*)alloc((size_t)256 * 512 * 2);
  int* btot_d = (int*)alloc((size_t)NBK * 4);
  int* btot_s = (int*)alloc((size_t)NBS * 4);
  int* bbase = (int*)alloc((size_t)(NBK + 1) * 4);
  int* bcur = (int*)alloc((size_t)NBK * 4);
  int* sbase = (int*)alloc((size_t)(NBS + 1) * 4);
  int* scur = (int*)alloc((size_t)NBS * 4);
  unsigned short* wgT3 = (unsigned short*)alloc((size_t)192 * NNP * 2);  // 19.3MB hi/lo/ind bf16
  float* zpart = (float*)alloc((size_t)PCHUNKS * ZR2 * F1 * 4);          // 14.7MB split-K partials
  // Aliasing inside aggb: recs (uint2, 6.4MB @0), srecs (uint, 3.2MB @6.4MB).
  // recs dead after k_csr; srecs dead after k_csc — both before k_agg2 writes
  // aggb. aggb pad rows [NN,NNP) are past the aliases and zeroed below so
  // gemm1's DMA of pad rows reads finite zeros.
  uint2* recs = (uint2*)aggb;
  unsigned int* srecs = (unsigned int*)(aggb + (size_t)NE * 4);

  hipMemsetAsync(btot_d, 0, (size_t)NBK * 4, stream);
  hipMemsetAsync(btot_s, 0, (size_t)NBS * 4, stream);
  hipMemsetAsync(p1, 0, (size_t)NG * F1 * 4, stream);
  hipMemsetAsync(z, 0, (size_t)NG * F1 * 4, stream);
  hipMemsetAsync(aggb + (size_t)NN * F1, 0, (size_t)(NNP - NN) * F1 * 2, stream);

  k_bhist<<<256, 256, 0, stream>>>(ei, btot_d, btot_s);
  k_bscan<<<1, 512, 0, stream>>>(btot_d, btot_s, bbase, bcur, sbase, scur, rowp);
  k_bscatter<<<SCB, 256, 0, stream>>>(ei, x, bcur, scur, recs, srecs);
  k_csr<<<NBK, 256, 0, stream>>>(recs, bbase, x, batch, rowp, ax, colx, dg);
  k_csc<<<NBS, 256, 0, stream>>>(srecs, sbase, dg, batch, (unsigned int*)wgT3);
  k_cnt<<<1, 64, 0, stream>>>(batch, cnt);
  k_axe<<<(NE + 255) / 256, 256, 0, stream>>>(colx, ax, axe);
  k_wprep<<<(256 * 512 + 255) / 256, 256, 0, stream>>>(Wl1, Wr1, wcat);
  k_agg2<<<2048, 256, 0, stream>>>(axe, rowp, Wl0, b0, Wr0, aggb);
  dim3 gg(392, 2);
  k_gemm1<<<gg, 256, 0, stream>>>(aggb, ax, wcat, Wl0, b0, Wr0, b1, h1T);
  k_poolmm<<<4 * PCHUNKS, 256, 0, stream>>>(h1T, wgT3, zpart);
  dim3 zg(NG, 8);
  k_zred<<<zg, 256, 0, stream>>>(zpart, z, p1);
  k_final<<<NG, 128, 0, stream>>>(z, p1, cnt, Wl2, b2, Wr2, gamma, beta, out);
}

// Round 12
// 192.206 us; speedup vs baseline: 1.0238x; 1.0238x over previous
//
#include <hip/hip_runtime.h>
#include <stdint.h>

#define NN 50000
#define NE 800000
#define NG 64
#define F1 256
#define NNP 50176    // padded node count: 392*128, multiple of 448 and 512
#define NBK 196      // dst buckets (d >> 8), 196*256 >= 50000
#define NBS 392      // src buckets (s >> 7), 392*128 = 50176 >= 50000
#define EPB 2048     // edges per k_bscatter block
#define SCB 391      // ceil(NE / EPB)
#define PCHUNKS 112  // k_poolmm K-chunks (112*448 = 50176 exactly)
#define PKC 448      // K per chunk = 7 * 64
#define PSTEPS 7     // BK=64 steps per chunk
#define ZR2 128      // zpart rows per chunk: 64 z-partial (hi+lo folded) + 64 ind

typedef __bf16 bf16x8 __attribute__((ext_vector_type(8)));
typedef float f32x4 __attribute__((ext_vector_type(4)));

__device__ __forceinline__ float bf2f(unsigned int u) {
  union { float f; unsigned int i; } v; v.i = (u & 0xffffu) << 16; return v.f;
}
__device__ __forceinline__ unsigned short f2bf(float f) {
  union { float f; unsigned int i; } v; v.f = f;
  unsigned int r = v.i + 0x7fffu + ((v.i >> 16) & 1u);
  return (unsigned short)(r >> 16);
}
__device__ __forceinline__ float asf(unsigned int u) {
  union { unsigned int u; float f; } v; v.u = u; return v.f;
}
__device__ __forceinline__ unsigned int asu(float f) {
  union { float f; unsigned int u; } v; v.f = f; return v.u;
}
// global->LDS DMA, 16B/lane. LDS dest is wave-uniform base + lane*16 (linear);
// swizzles must be applied on the per-lane GLOBAL source address (rule #21).
__device__ __forceinline__ void gload16(const void* g, void* l) {
  __builtin_amdgcn_global_load_lds(
      (const __attribute__((address_space(1))) unsigned int*)g,
      (__attribute__((address_space(3))) unsigned int*)l, 16, 0, 0);
}

// ---- K1: dual coarse histograms (dst>>8 and src>>7), LDS-merged ----
__global__ void k_bhist(const int* __restrict__ ei, int* __restrict__ btot_d,
                        int* __restrict__ btot_s) {
  __shared__ int lhd[NBK];
  __shared__ int lhs[NBS];
  for (int i = threadIdx.x; i < NBK; i += 256) lhd[i] = 0;
  for (int i = threadIdx.x; i < NBS; i += 256) lhs[i] = 0;
  __syncthreads();
  for (int e = blockIdx.x * blockDim.x + threadIdx.x; e < NE; e += gridDim.x * blockDim.x) {
    atomicAdd(&lhs[ei[e] >> 7], 1);
    atomicAdd(&lhd[ei[NE + e] >> 8], 1);
  }
  __syncthreads();
  for (int i = threadIdx.x; i < NBK; i += 256) atomicAdd(&btot_d[i], lhd[i]);
  for (int i = threadIdx.x; i < NBS; i += 256) atomicAdd(&btot_s[i], lhs[i]);
}

// ---- K2: scan both bucket-total arrays -> bases/cursors; rowp[NN]=NE ----
__global__ void k_bscan(const int* __restrict__ btot_d, const int* __restrict__ btot_s,
                        int* __restrict__ bbase, int* __restrict__ bcur,
                        int* __restrict__ sbase, int* __restrict__ scur,
                        int* __restrict__ rowp) {
  __shared__ int buf[512];
  int t = threadIdx.x;
  int v = (t < NBK) ? btot_d[t] : 0;
  buf[t] = v;
  __syncthreads();
  for (int off = 1; off < 512; off <<= 1) {
    int o = (t >= off) ? buf[t - off] : 0;
    __syncthreads();
    buf[t] += o;
    __syncthreads();
  }
  if (t < NBK) { bbase[t] = buf[t] - v; bcur[t] = buf[t] - v; }
  if (t == NBK - 1) bbase[NBK] = buf[t];
  __syncthreads();
  int v2 = (t < NBS) ? btot_s[t] : 0;
  buf[t] = v2;
  __syncthreads();
  for (int off = 1; off < 512; off <<= 1) {
    int o = (t >= off) ? buf[t - off] : 0;
    __syncthreads();
    buf[t] += o;
    __syncthreads();
  }
  if (t < NBS) { sbase[t] = buf[t] - v2; scur[t] = buf[t] - v2; }
  if (t == NBS - 1) sbase[NBS] = buf[t];
  if (t == 0) rowp[NN] = NE;
}

// ---- K3: dual scatter: dst-records {s|d<<16, x[s]} and src-records {d|sl<<16} ----
__global__ __launch_bounds__(256) void k_bscatter(
    const int* __restrict__ ei, const float* __restrict__ x,
    int* __restrict__ bcur, int* __restrict__ scur,
    uint2* __restrict__ recs, unsigned int* __restrict__ srecs) {
  __shared__ int lhd[NBK]; __shared__ int gbd[NBK];
  __shared__ int lhs[NBS]; __shared__ int gbs[NBS];
  int b = blockIdx.x, tid = threadIdx.x;
  int e0 = b * EPB;
  for (int i = tid; i < NBK; i += 256) lhd[i] = 0;
  for (int i = tid; i < NBS; i += 256) lhs[i] = 0;
  __syncthreads();
  unsigned int meta[8]; float xv[8]; int lofd[8]; int bkd[8]; int lofs[8]; int bks[8];
#pragma unroll
  for (int i = 0; i < 8; ++i) {
    int e = e0 + i * 256 + tid;
    bkd[i] = -1;
    if (e < NE) {
      int s = ei[e], d = ei[NE + e];
      bkd[i] = d >> 8; bks[i] = s >> 7;
      meta[i] = (unsigned int)s | ((unsigned int)d << 16);  // s,d < 65536
      xv[i] = x[s];
      lofd[i] = atomicAdd(&lhd[bkd[i]], 1);
      lofs[i] = atomicAdd(&lhs[bks[i]], 1);
    }
  }
  __syncthreads();
  for (int i = tid; i < NBK; i += 256) gbd[i] = atomicAdd(&bcur[i], lhd[i]);
  for (int i = tid; i < NBS; i += 256) gbs[i] = atomicAdd(&scur[i], lhs[i]);
  __syncthreads();
#pragma unroll
  for (int i = 0; i < 8; ++i) {
    if (bkd[i] >= 0) {
      recs[gbd[bkd[i]] + lofd[i]] = make_uint2(meta[i], asu(xv[i]));
      unsigned int s = meta[i] & 0xFFFFu, d = meta[i] >> 16;
      srecs[gbs[bks[i]] + lofs[i]] = d | ((s & 127u) << 16);
    }
  }
}

// ---- K4: per-dst-bucket fine CSR + per-node ax + dg table + colx scatter ----
__global__ __launch_bounds__(256) void k_csr(
    const uint2* __restrict__ recs, const int* __restrict__ bbase,
    const float* __restrict__ x, const int* __restrict__ batch,
    int* __restrict__ rowp, float2* __restrict__ ax,
    int* __restrict__ colx, uint2* __restrict__ dg) {
  __shared__ int cnt[256];
  __shared__ int sc[256];
  __shared__ float xs[256];
  int b = blockIdx.x, tid = threadIdx.x;
  int eb = bbase[b], ee = bbase[b + 1];
  cnt[tid] = 0;
  xs[tid] = 0.0f;
  __syncthreads();
  for (int e = eb + tid; e < ee; e += 256) {
    uint2 r = recs[e];
    int dl = (r.x >> 16) & 255;
    atomicAdd(&cnt[dl], 1);
    atomicAdd(&xs[dl], asf(r.y));
  }
  __syncthreads();
  sc[tid] = cnt[tid];
  __syncthreads();
  for (int off = 1; off < 256; off <<= 1) {
    int o = (tid >= off) ? sc[tid - off] : 0;
    __syncthreads();
    sc[tid] += o;
    __syncthreads();
  }
  int excl = sc[tid] - cnt[tid];
  int i = b * 256 + tid;
  float dinv = 1.0f / fmaxf((float)cnt[tid], 1.0f);
  if (i < NN) {
    rowp[i] = eb + excl;
    ax[i] = make_float2(xs[tid] * dinv, x[i]);
    dg[i] = make_uint2(asu(dinv), (unsigned int)batch[i]);
  }
  __syncthreads();
  sc[tid] = excl;  // cursor
  __syncthreads();
  for (int e = eb + tid; e < ee; e += 256) {
    uint2 r = recs[e];
    int dl = (r.x >> 16) & 255;
    int s = r.x & 0xFFFF;
    int slot = atomicAdd(&sc[dl], 1);
    colx[eb + slot] = s;
  }
}

// ---- K5: per-src-bucket wg rows in LDS; emit TRANSPOSED bf16 wgT3 ----
// wgT3[g'][s]: rows 0..63 = bf16(wg) (hi), 64..127 = bf16(wg - hi) (lo),
// 128..191 = indicator bf16(batch[s]==g ? 1 : 0). Pad cols (s>=NN): all 0.
__global__ __launch_bounds__(256) void k_csc(
    const unsigned int* __restrict__ srecs, const int* __restrict__ sbase,
    const uint2* __restrict__ dg, const int* __restrict__ batch,
    unsigned int* __restrict__ wgT3u) {
  __shared__ float wgrow[128 * 65];  // [sl][g], pad 65 to break readout conflicts
  __shared__ int sbt[128];
  int b = blockIdx.x, tid = threadIdx.x;
  for (int i = tid; i < 128 * 65; i += 256) wgrow[i] = 0.0f;
  if (tid < 128) {
    int s = b * 128 + tid;
    sbt[tid] = (s < NN) ? batch[s] : -1;
  }
  __syncthreads();
  int eb = sbase[b], ee = sbase[b + 1];
  for (int e = eb + tid; e < ee; e += 256) {
    unsigned int r = srecs[e];
    int d = r & 0xFFFF;
    int sl = (r >> 16) & 127;
    uint2 t = dg[d];  // {deginv bits, g} — 400KB table, L2-resident
    atomicAdd(&wgrow[sl * 65 + t.y], asf(t.x));
  }
  __syncthreads();
  int s0u = b * 64;  // u32 column base (= b*128 bf16 cols / 2)
  int k = tid & 63;
  for (int rr = 0; rr < 16; ++rr) {
    int g = rr * 4 + (tid >> 6);
    float w0 = wgrow[(2 * k) * 65 + g];
    float w1 = wgrow[(2 * k + 1) * 65 + g];
    unsigned short h0 = f2bf(w0), h1v = f2bf(w1);
    unsigned short l0 = f2bf(w0 - bf2f(h0)), l1 = f2bf(w1 - bf2f(h1v));
    wgT3u[(size_t)g * (NNP / 2) + s0u + k] = (unsigned int)h0 | ((unsigned int)h1v << 16);
    wgT3u[(size_t)(64 + g) * (NNP / 2) + s0u + k] = (unsigned int)l0 | ((unsigned int)l1 << 16);
  }
  int bv0 = sbt[2 * k], bv1 = sbt[2 * k + 1];
  for (int rr = 0; rr < 16; ++rr) {
    int g = rr * 4 + (tid >> 6);
    unsigned int u = ((bv0 == g) ? 0x3F80u : 0u) | ((bv1 == g) ? 0x3F800000u : 0u);
    wgT3u[(size_t)(128 + g) * (NNP / 2) + s0u + k] = u;
  }
}

// ---- per-graph node count via binary search over sorted batch ----
__global__ void k_cnt(const int* __restrict__ batch, int* __restrict__ cnt) {
  int g = threadIdx.x;
  if (g >= NG) return;
  int lo = 0, hi = NN;
  while (lo < hi) { int m = (lo + hi) >> 1; if (batch[m] < g) lo = m + 1; else hi = m; }
  int a = lo;
  lo = 0; hi = NN;
  while (lo < hi) { int m = (lo + hi) >> 1; if (batch[m] < g + 1) lo = m + 1; else hi = m; }
  cnt[g] = lo - a;
}

// ---- materialize edge-ordered (a0,x): coalesced write, small-table gather ----
// ax is 400KB L2-resident; decoupling this gather from agg2's compute is the
// R7-proven structure (R8/R9/R11 fused/restructured variants all regressed).
__global__ void k_axe(const int* __restrict__ colx, const float2* __restrict__ ax,
                      float2* __restrict__ axe) {
  int e = blockIdx.x * blockDim.x + threadIdx.x;
  if (e >= NE) return;
  axe[e] = ax[colx[e]];
}

// ---- wcat[n][k]: k<256 -> Wl1[k][n], else Wr1[k-256][n] ----
__global__ void k_wprep(const float* __restrict__ Wl1, const float* __restrict__ Wr1,
                        unsigned short* __restrict__ wcat) {
  int t = blockIdx.x * blockDim.x + threadIdx.x;
  if (t >= 256 * 512) return;
  int n = t >> 9, k = t & 511;
  float v = (k < 256) ? Wl1[k * 256 + n] : Wr1[(k - 256) * 256 + n];
  wcat[t] = f2bf(v);
}

// ---- layer-1 mean-aggregation: stream edge-ordered axe (R7 form, 8/iter) ----
// R7's plain 4-edge loop is the proven-best structure (R8 gather, R9 rotation,
// R11 pk_fma asm all regressed — they fight the compiler's schedule). This
// round's single change: widen the batch to 8 edges/iter -> 8 independent
// broadcast loads in flight per iteration top (targets the ~40% latency gap
// at VALUBusy ~58%), same instruction mix otherwise.
__global__ __launch_bounds__(256) void k_agg2(
    const float2* __restrict__ axe, const int* __restrict__ rowp,
    const float* __restrict__ Wl0, const float* __restrict__ b0,
    const float* __restrict__ Wr0, unsigned short* __restrict__ aggb) {
  int wid = threadIdx.x >> 6, lane = threadIdx.x & 63;
  int gw = blockIdx.x * 4 + wid;
  int tw = gridDim.x * 4;
  float wl[4], wr[4], bb[4];
#pragma unroll
  for (int k = 0; k < 4; ++k) {
    wl[k] = Wl0[lane * 4 + k];
    wr[k] = Wr0[lane * 4 + k];
    bb[k] = b0[lane * 4 + k];
  }
  for (int d = gw; d < NN; d += tw) {
    int beg = rowp[d], end = rowp[d + 1];
    float a[4] = {0.f, 0.f, 0.f, 0.f};
    float c[4] = {0.f, 0.f, 0.f, 0.f};
    int e = beg;
    for (; e + 7 < end; e += 8) {
      float2 v0 = axe[e], v1 = axe[e + 1], v2 = axe[e + 2], v3 = axe[e + 3];
      float2 v4 = axe[e + 4], v5 = axe[e + 5], v6 = axe[e + 6], v7 = axe[e + 7];
#pragma unroll
      for (int k = 0; k < 4; ++k) {
        a[k] += fmaxf(fmaf(v0.x, wl[k], fmaf(v0.y, wr[k], bb[k])), 0.0f);
        c[k] += fmaxf(fmaf(v1.x, wl[k], fmaf(v1.y, wr[k], bb[k])), 0.0f);
        a[k] += fmaxf(fmaf(v2.x, wl[k], fmaf(v2.y, wr[k], bb[k])), 0.0f);
        c[k] += fmaxf(fmaf(v3.x, wl[k], fmaf(v3.y, wr[k], bb[k])), 0.0f);
        a[k] += fmaxf(fmaf(v4.x, wl[k], fmaf(v4.y, wr[k], bb[k])), 0.0f);
        c[k] += fmaxf(fmaf(v5.x, wl[k], fmaf(v5.y, wr[k], bb[k])), 0.0f);
        a[k] += fmaxf(fmaf(v6.x, wl[k], fmaf(v6.y, wr[k], bb[k])), 0.0f);
        c[k] += fmaxf(fmaf(v7.x, wl[k], fmaf(v7.y, wr[k], bb[k])), 0.0f);
      }
    }
    for (; e + 3 < end; e += 4) {
      float2 v0 = axe[e], v1 = axe[e + 1], v2 = axe[e + 2], v3 = axe[e + 3];
#pragma unroll
      for (int k = 0; k < 4; ++k) {
        a[k] += fmaxf(fmaf(v0.x, wl[k], fmaf(v0.y, wr[k], bb[k])), 0.0f);
        c[k] += fmaxf(fmaf(v1.x, wl[k], fmaf(v1.y, wr[k], bb[k])), 0.0f);
        a[k] += fmaxf(fmaf(v2.x, wl[k], fmaf(v2.y, wr[k], bb[k])), 0.0f);
        c[k] += fmaxf(fmaf(v3.x, wl[k], fmaf(v3.y, wr[k], bb[k])), 0.0f);
      }
    }
    for (; e < end; ++e) {
      float2 v0 = axe[e];
#pragma unroll
      for (int k = 0; k < 4; ++k)
        a[k] += fmaxf(fmaf(v0.x, wl[k], fmaf(v0.y, wr[k], bb[k])), 0.0f);
    }
    float dinv = 1.0f / fmaxf((float)(end - beg), 1.0f);
    uint2 o;
    o.x = (unsigned int)f2bf((a[0] + c[0]) * dinv) | ((unsigned int)f2bf((a[1] + c[1]) * dinv) << 16);
    o.y = (unsigned int)f2bf((a[2] + c[2]) * dinv) | ((unsigned int)f2bf((a[3] + c[3]) * dinv) << 16);
    *(uint2*)(aggb + (size_t)d * F1 + lane * 4) = o;
  }
}

// ---- layer 1 GEMM (R7-exact: LDS double-buffer BK=32, reg-staged, fused h0) ----
// Epilogue writes h1T[f][s] directly: unswapped mfma(af,bfr) puts 4
// consecutive s per lane at fixed f -> 8B uint2 stores, no LDS transpose.
#define BM 128
#define BN 128
#define BK 32

__global__ __launch_bounds__(256) void k_gemm1(
    const unsigned short* __restrict__ aggb, const float2* __restrict__ ax,
    const unsigned short* __restrict__ wcat,
    const float* __restrict__ Wl0, const float* __restrict__ b0,
    const float* __restrict__ Wr0, const float* __restrict__ b1,
    unsigned short* __restrict__ h1T) {
  __shared__ unsigned short As[2][BM][BK];
  __shared__ unsigned short Bs[2][BN][BK];
  __shared__ float wl0s[256], wr0s[256], b0s[256];
  int bm = blockIdx.x, ct = blockIdx.y;
  int tid = threadIdx.x;
  int wid = tid >> 6, lane = tid & 63;
  int wr = wid >> 1, wc = wid & 1;
  int rc = lane & 15, kh = lane >> 4;
  int r0 = bm * BM;
  int srow = tid >> 1;   // 0..127: one staged row per thread
  int sslot = tid & 1;   // which 32B half of the 64B k-row

  wl0s[tid] = Wl0[tid];
  wr0s[tid] = Wr0[tid];
  b0s[tid] = b0[tid];

  int rA = r0 + srow;
  bool rAok = rA < NN;
  float2 axv = rAok ? ax[rA] : make_float2(0.f, 0.f);

  f32x4 acc[4][4] = {};  // acc[mf][nf]: rows (kh,j) <-> s, col rc <-> f
  int4 ra0, ra1, rb0, rb1;

#define LOAD_A(kt)                                                             \
  do {                                                                         \
    ra0 = make_int4(0, 0, 0, 0); ra1 = make_int4(0, 0, 0, 0);                  \
    if (rAok) {                                                                \
      const int4* s_ = (const int4*)(aggb + (size_t)rA * F1 + (kt) * BK + sslot * 16); \
      ra0 = s_[0]; ra1 = s_[1];                                                \
    }                                                                          \
  } while (0)

#define LOAD_B(kt)                                                             \
  do {                                                                         \
    const int4* t_ = (const int4*)(wcat + (size_t)(ct * BN + srow) * 512 + (kt) * BK + sslot * 16); \
    rb0 = t_[0]; rb1 = t_[1];                                                  \
  } while (0)

// h0[rA][j] = relu(ax.x*Wl0[j] + ax.y*Wr0[j] + b0[j]) — bit-identical to old k_h0
#define COMP_A(kt)                                                             \
  do {                                                                         \
    int j0_ = ((kt) - 8) * BK + sslot * 16;                                    \
    unsigned int w_[8];                                                        \
    _Pragma("unroll") for (int q = 0; q < 8; ++q) {                            \
      int j_ = j0_ + 2 * q;                                                    \
      float f0_ = fmaxf(fmaf(axv.x, wl0s[j_], fmaf(axv.y, wr0s[j_], b0s[j_])), 0.0f); \
      float f1_ = fmaxf(fmaf(axv.x, wl0s[j_ + 1], fmaf(axv.y, wr0s[j_ + 1], b0s[j_ + 1])), 0.0f); \
      w_[q] = (unsigned int)f2bf(f0_) | ((unsigned int)f2bf(f1_) << 16);       \
    }                                                                          \
    ra0 = make_int4(w_[0], w_[1], w_[2], w_[3]);                               \
    ra1 = make_int4(w_[4], w_[5], w_[6], w_[7]);                               \
  } while (0)

// swizzle: 4 16B slots/row, phys = logical ^ ((row>>1)&3) -> 2-way (free) on read
#define WRITE_AB(buf)                                                          \
  do {                                                                         \
    int sw_ = (srow >> 1) & 3;                                                 \
    int ws0_ = (2 * sslot) ^ sw_;                                              \
    int ws1_ = (2 * sslot + 1) ^ sw_;                                          \
    *(int4*)&As[buf][srow][ws0_ * 8] = ra0;                                    \
    *(int4*)&As[buf][srow][ws1_ * 8] = ra1;                                    \
    *(int4*)&Bs[buf][srow][ws0_ * 8] = rb0;                                    \
    *(int4*)&Bs[buf][srow][ws1_ * 8] = rb1;                                    \
  } while (0)

  LOAD_B(0);
  LOAD_A(0);
  WRITE_AB(0);
  __syncthreads();
  int cur = 0;
  for (int kt = 0; kt < 16; ++kt) {
    if (kt < 15) {
      LOAD_B(kt + 1);
      if (kt + 1 < 8) LOAD_A(kt + 1);
    }
    bf16x8 af[4], bfr[4];
#pragma unroll
    for (int mf = 0; mf < 4; ++mf) {
      int row = wr * 64 + mf * 16 + rc;
      int sl = kh ^ ((row >> 1) & 3);
      af[mf] = *(const bf16x8*)&As[cur][row][sl * 8];
    }
#pragma unroll
    for (int nf = 0; nf < 4; ++nf) {
      int row = wc * 64 + nf * 16 + rc;
      int sl = kh ^ ((row >> 1) & 3);
      bfr[nf] = *(const bf16x8*)&Bs[cur][row][sl * 8];
    }
#pragma unroll
    for (int mf = 0; mf < 4; ++mf)
#pragma unroll
      for (int nf = 0; nf < 4; ++nf)
        acc[mf][nf] = __builtin_amdgcn_mfma_f32_16x16x32_bf16(af[mf], bfr[nf], acc[mf][nf], 0, 0, 0);
    if (kt < 15) {
      if (kt + 1 >= 8) COMP_A(kt + 1);
      WRITE_AB(cur ^ 1);
    }
    __syncthreads();
    cur ^= 1;
  }
#undef LOAD_A
#undef LOAD_B
#undef COMP_A
#undef WRITE_AB

  // ---- epilogue: bias+relu, direct h1T[f][s] 8B stores ----
#pragma unroll
  for (int nf = 0; nf < 4; ++nf) {
    int f = ct * BN + wc * 64 + nf * 16 + rc;
    float bias = b1[f];
    size_t frow = (size_t)f * NNP;
#pragma unroll
    for (int mf = 0; mf < 4; ++mf) {
      int s0 = r0 + wr * 64 + mf * 16 + kh * 4;
      f32x4 a = acc[mf][nf];
      unsigned int lo = (unsigned int)f2bf(fmaxf(a[0] + bias, 0.0f)) |
                        ((unsigned int)f2bf(fmaxf(a[1] + bias, 0.0f)) << 16);
      unsigned int hi = (unsigned int)f2bf(fmaxf(a[2] + bias, 0.0f)) |
                        ((unsigned int)f2bf(fmaxf(a[3] + bias, 0.0f)) << 16);
      *(uint2*)(h1T + frow + s0) = make_uint2(lo, hi);
    }
  }
}

// ---- pool contraction: global_load_lds double-buffered MFMA streamer ----
// (R7 structure, unchanged — 189us round verified.)
__global__ __launch_bounds__(256, 2) void k_poolmm(
    const unsigned short* __restrict__ h1T, const unsigned short* __restrict__ wgT3,
    float* __restrict__ zpart) {
  __shared__ unsigned short SM[2][2048 * 8];  // 2 x 32KB: slots 0..1535 = A(192 rows), 1536..2047 = B(64 rows)
  int bid = blockIdx.x;
  int lbid = (bid & 7) * 56 + (bid >> 3);  // XCD-bucket: 4 f-slices of a chunk share an XCD
  int c = lbid >> 2, fs = lbid & 3;
  int tid = threadIdx.x;
  int w = tid >> 6, lane = tid & 63, rc = lane & 15, kh = lane >> 4;
  int kbase = c * PKC;
  int fbase = fs * 64;

  const unsigned short* gsrc[8];
#pragma unroll
  for (int r = 0; r < 8; ++r) {
    int sIdx = r * 256 + tid;
    if (sIdx < 1536) {
      int row = sIdx >> 3, sl = sIdx & 7;
      gsrc[r] = wgT3 + (size_t)row * NNP + kbase + (sl ^ (row & 7)) * 8;
    } else {
      int row = (sIdx - 1536) >> 3, sl = sIdx & 7;
      gsrc[r] = h1T + (size_t)(fbase + row) * NNP + kbase + (sl ^ (row & 7)) * 8;
    }
  }

  f32x4 acc[12] = {};

#define PSTAGE(buf, t)                                                         \
  do {                                                                         \
    _Pragma("unroll") for (int r = 0; r < 8; ++r)                              \
      gload16(gsrc[r] + (t) * 64, &SM[buf][(r * 256 + w * 64) * 8]);           \
  } while (0)

#define PCOMP(buf)                                                             \
  do {                                                                         \
    _Pragma("unroll") for (int ks = 0; ks < 2; ++ks) {                         \
      int brow = w * 16 + rc;                                                  \
      int bsl = (ks * 4 + kh) ^ (brow & 7);                                    \
      bf16x8 bf = *(const bf16x8*)&SM[buf][(1536 + brow * 8 + bsl) * 8];       \
      _Pragma("unroll") for (int mt = 0; mt < 12; ++mt) {                      \
        int arow = mt * 16 + rc;                                               \
        int asl = (ks * 4 + kh) ^ (arow & 7);                                  \
        bf16x8 af = *(const bf16x8*)&SM[buf][(arow * 8 + asl) * 8];            \
        acc[mt] = __builtin_amdgcn_mfma_f32_16x16x32_bf16(af, bf, acc[mt], 0, 0, 0); \
      }                                                                        \
    }                                                                          \
  } while (0)

  PSTAGE(0, 0);
  __syncthreads();
#pragma unroll
  for (int t = 0; t < PSTEPS; ++t) {
    int buf = t & 1;
    if (t + 1 < PSTEPS) PSTAGE(buf ^ 1, t + 1);
    PCOMP(buf);
    __syncthreads();
  }
#undef PSTAGE
#undef PCOMP

  float* zp = zpart + ((size_t)c * ZR2) * F1 + fbase + w * 16 + rc;
#pragma unroll
  for (int mt = 0; mt < 4; ++mt)
#pragma unroll
    for (int r = 0; r < 4; ++r)
      zp[(size_t)(mt * 16 + kh * 4 + r) * F1] = acc[mt][r] + acc[mt + 4][r];
#pragma unroll
  for (int mt = 8; mt < 12; ++mt)
#pragma unroll
    for (int r = 0; r < 4; ++r)
      zp[(size_t)((mt - 8) * 16 + 64 + kh * 4 + r) * F1] = acc[mt][r];
}

// ---- zpart reduction: z[g][f] = sum_c zrow, p1[g][f] = sum_c ind ----
__global__ void k_zred(const float* __restrict__ zpart, float* __restrict__ z,
                       float* __restrict__ p1) {
  int g = blockIdx.x, q = blockIdx.y, t = threadIdx.x;  // grid (64, 8)
  float a = 0.0f, b = 0.0f;
  for (int c = q * 14; c < q * 14 + 14; ++c) {
    const float* base = zpart + (size_t)c * ZR2 * F1;
    a += base[(size_t)g * F1 + t];
    b += base[(size_t)(64 + g) * F1 + t];
  }
  atomicAdd(&z[g * F1 + t], a);
  atomicAdd(&p1[g * F1 + t], b);
}

// ---- final: g = (Z/cnt)@Wl2 + b2 + (P/cnt)@Wr2, then LayerNorm ----
__global__ void k_final(const float* __restrict__ z, const float* __restrict__ p1,
                        const int* __restrict__ cnt,
                        const float* __restrict__ Wl2, const float* __restrict__ b2,
                        const float* __restrict__ Wr2, const float* __restrict__ gamma,
                        const float* __restrict__ beta, float* __restrict__ out) {
  __shared__ float s1[128], s2[128];
  int g = blockIdx.x, j = threadIdx.x;
  float invc = 1.0f / fmaxf((float)cnt[g], 1.0f);
  float acc = 0.0f;
  for (int k = 0; k < 256; ++k) {
    acc += z[g * 256 + k] * Wl2[k * 128 + j] + p1[g * 256 + k] * Wr2[k * 128 + j];
  }
  acc = acc * invc + b2[j];
  s1[j] = acc; s2[j] = acc * acc;
  __syncthreads();
  for (int off = 64; off > 0; off >>= 1) {
    if (j < off) { s1[j] += s1[j + off]; s2[j] += s2[j + off]; }
    __syncthreads();
  }
  float mu = s1[0] / 128.0f;
  float var = s2[0] / 128.0f - mu * mu;
  out[g * 128 + j] = (acc - mu) * rsqrtf(var + 1e-5f) * gamma[j] + beta[j];
}

extern "C" void kernel_launch(void* const* d_in, const int* in_sizes, int n_in,
                              void* d_out, int out_size, void* d_ws, size_t ws_size,
                              hipStream_t stream) {
  const float* x = (const float*)d_in[0];
  const int* ei = (const int*)d_in[1];
  const int* batch = (const int*)d_in[2];
  const float* Wl0 = (const float*)d_in[3];
  const float* b0 = (const float*)d_in[4];
  const float* Wr0 = (const float*)d_in[5];
  const float* Wl1 = (const float*)d_in[6];
  const float* b1 = (const float*)d_in[7];
  const float* Wr1 = (const float*)d_in[8];
  const float* Wl2 = (const float*)d_in[9];
  const float* b2 = (const float*)d_in[10];
  const float* Wr2 = (const float*)d_in[11];
  const float* gamma = (const float*)d_in[12];
  const float* beta = (const float*)d_in[13];
  float* out = (float*)d_out;

  char* p = (char*)d_ws;
  auto alloc = [&](size_t bytes) {
    char* r = p;
    p += (bytes + 511) & ~(size_t)511;
    return r;
  };
  unsigned short* h1T = (unsigned short*)alloc((size_t)F1 * NNP * 2);    // 25.7MB transposed h1
  unsigned short* aggb = (unsigned short*)alloc((size_t)NNP * F1 * 2);   // padded to NNP rows; hosts recs+srecs early
  int* colx = (int*)alloc((size_t)NE * 4);                               // 3.2MB
  float2* axe = (float2*)alloc((size_t)NE * 8);                          // 6.4MB edge-ordered (a0,x)
  int* rowp = (int*)alloc((size_t)(NN + 1) * 4);
  float2* ax = (float2*)alloc((size_t)NN * 8);
  uint2* dg = (uint2*)alloc((size_t)NN * 8);
  int* cnt = (int*)alloc((size_t)NG * 4);
  float* z = (float*)alloc((size_t)NG * F1 * 4);
  float* p1 = (float*)alloc((size_t)NG * F1 * 4);
  unsigned short* wcat = (unsigned short*)alloc((size_t)256 * 512 * 2);
  int* btot_d = (int*)alloc((size_t)NBK * 4);
  int* btot_s = (int*)alloc((size_t)NBS * 4);
  int* bbase = (int*)alloc((size_t)(NBK + 1) * 4);
  int* bcur = (int*)alloc((size_t)NBK * 4);
  int* sbase = (int*)alloc((size_t)(NBS + 1) * 4);
  int* scur = (int*)alloc((size_t)NBS * 4);
  unsigned short* wgT3 = (unsigned short*)alloc((size_t)192 * NNP * 2);  // 19.3MB hi/lo/ind bf16
  float* zpart = (float*)alloc((size_t)PCHUNKS * ZR2 * F1 * 4);          // 14.7MB split-K partials
  // Aliasing inside aggb: recs (uint2, 6.4MB @0), srecs (uint, 3.2MB @6.4MB).
  // recs dead after k_csr; srecs dead after k_csc — both before k_agg2 writes
  // aggb. aggb pad rows [NN,NNP) are past the aliases and zeroed below.
  uint2* recs = (uint2*)aggb;
  unsigned int* srecs = (unsigned int*)(aggb + (size_t)NE * 4);

  hipMemsetAsync(btot_d, 0, (size_t)NBK * 4, stream);
  hipMemsetAsync(btot_s, 0, (size_t)NBS * 4, stream);
  hipMemsetAsync(p1, 0, (size_t)NG * F1 * 4, stream);
  hipMemsetAsync(z, 0, (size_t)NG * F1 * 4, stream);
  hipMemsetAsync(aggb + (size_t)NN * F1, 0, (size_t)(NNP - NN) * F1 * 2, stream);

  k_bhist<<<256, 256, 0, stream>>>(ei, btot_d, btot_s);
  k_bscan<<<1, 512, 0, stream>>>(btot_d, btot_s, bbase, bcur, sbase, scur, rowp);
  k_bscatter<<<SCB, 256, 0, stream>>>(ei, x, bcur, scur, recs, srecs);
  k_csr<<<NBK, 256, 0, stream>>>(recs, bbase, x, batch, rowp, ax, colx, dg);
  k_csc<<<NBS, 256, 0, stream>>>(srecs, sbase, dg, batch, (unsigned int*)wgT3);
  k_cnt<<<1, 64, 0, stream>>>(batch, cnt);
  k_axe<<<(NE + 255) / 256, 256, 0, stream>>>(colx, ax, axe);
  k_wprep<<<(256 * 512 + 255) / 256, 256, 0, stream>>>(Wl1, Wr1, wcat);
  k_agg2<<<2048, 256, 0, stream>>>(axe, rowp, Wl0, b0, Wr0, aggb);
  dim3 gg(392, 2);
  k_gemm1<<<gg, 256, 0, stream>>>(aggb, ax, wcat, Wl0, b0, Wr0, b1, h1T);
  k_poolmm<<<4 * PCHUNKS, 256, 0, stream>>>(h1T, wgT3, zpart);
  dim3 zg(NG, 8);
  k_zred<<<zg, 256, 0, stream>>>(zpart, z, p1);
  k_final<<<NG, 128, 0, stream>>>(z, p1, cnt, Wl2, b2, Wr2, gamma, beta, out);
}

// Round 13
// 180.370 us; speedup vs baseline: 1.0909x; 1.0656x over previous
//
#include <hip/hip_runtime.h>
#include <stdint.h>

#define NN 50000
#define NE 800000
#define NG 64
#define F1 256
#define NNP 50176    // padded node count: 392*128, multiple of 448 and 512
#define NBK 196      // dst buckets (d >> 8), 196*256 >= 50000
#define NBS 392      // src buckets (s >> 7), 392*128 = 50176 >= 50000
#define EPB 2048     // edges per k_bscatter block
#define SCB 391      // ceil(NE / EPB)
#define PCHUNKS 112  // k_poolmm K-chunks (112*448 = 50176 exactly)
#define PKC 448      // K per chunk = 7 * 64
#define PSTEPS 7     // BK=64 steps per chunk
#define ZR2 128      // zpart rows per chunk: 64 z-partial (hi+lo folded) + 64 ind

typedef __bf16 bf16x8 __attribute__((ext_vector_type(8)));
typedef float f32x4 __attribute__((ext_vector_type(4)));

__device__ __forceinline__ float bf2f(unsigned int u) {
  union { float f; unsigned int i; } v; v.i = (u & 0xffffu) << 16; return v.f;
}
__device__ __forceinline__ unsigned short f2bf(float f) {
  union { float f; unsigned int i; } v; v.f = f;
  unsigned int r = v.i + 0x7fffu + ((v.i >> 16) & 1u);
  return (unsigned short)(r >> 16);
}
__device__ __forceinline__ float asf(unsigned int u) {
  union { unsigned int u; float f; } v; v.u = u; return v.f;
}
__device__ __forceinline__ unsigned int asu(float f) {
  union { float f; unsigned int u; } v; v.f = f; return v.u;
}
// global->LDS DMA, 16B/lane. LDS dest is wave-uniform base + lane*16 (linear);
// swizzles must be applied on the per-lane GLOBAL source address (rule #21).
__device__ __forceinline__ void gload16(const void* g, void* l) {
  __builtin_amdgcn_global_load_lds(
      (const __attribute__((address_space(1))) unsigned int*)g,
      (__attribute__((address_space(3))) unsigned int*)l, 16, 0, 0);
}

// ---- K1: dual coarse histograms (dst>>8 and src>>7), LDS-merged ----
__global__ void k_bhist(const int* __restrict__ ei, int* __restrict__ btot_d,
                        int* __restrict__ btot_s) {
  __shared__ int lhd[NBK];
  __shared__ int lhs[NBS];
  for (int i = threadIdx.x; i < NBK; i += 256) lhd[i] = 0;
  for (int i = threadIdx.x; i < NBS; i += 256) lhs[i] = 0;
  __syncthreads();
  for (int e = blockIdx.x * blockDim.x + threadIdx.x; e < NE; e += gridDim.x * blockDim.x) {
    atomicAdd(&lhs[ei[e] >> 7], 1);
    atomicAdd(&lhd[ei[NE + e] >> 8], 1);
  }
  __syncthreads();
  for (int i = threadIdx.x; i < NBK; i += 256) atomicAdd(&btot_d[i], lhd[i]);
  for (int i = threadIdx.x; i < NBS; i += 256) atomicAdd(&btot_s[i], lhs[i]);
}

// ---- K2: scan both bucket totals -> bases/cursors; rowp[NN]=NE; + k_cnt tail ----
__global__ void k_bscan(const int* __restrict__ btot_d, const int* __restrict__ btot_s,
                        int* __restrict__ bbase, int* __restrict__ bcur,
                        int* __restrict__ sbase, int* __restrict__ scur,
                        int* __restrict__ rowp, const int* __restrict__ batch,
                        int* __restrict__ cnt) {
  __shared__ int buf[512];
  int t = threadIdx.x;
  int v = (t < NBK) ? btot_d[t] : 0;
  buf[t] = v;
  __syncthreads();
  for (int off = 1; off < 512; off <<= 1) {
    int o = (t >= off) ? buf[t - off] : 0;
    __syncthreads();
    buf[t] += o;
    __syncthreads();
  }
  if (t < NBK) { bbase[t] = buf[t] - v; bcur[t] = buf[t] - v; }
  if (t == NBK - 1) bbase[NBK] = buf[t];
  __syncthreads();
  int v2 = (t < NBS) ? btot_s[t] : 0;
  buf[t] = v2;
  __syncthreads();
  for (int off = 1; off < 512; off <<= 1) {
    int o = (t >= off) ? buf[t - off] : 0;
    __syncthreads();
    buf[t] += o;
    __syncthreads();
  }
  if (t < NBS) { sbase[t] = buf[t] - v2; scur[t] = buf[t] - v2; }
  if (t == NBS - 1) sbase[NBS] = buf[t];
  if (t == 0) rowp[NN] = NE;
  // folded k_cnt: per-graph node count via binary search over sorted batch
  if (t < NG) {
    int g = t;
    int lo = 0, hi = NN;
    while (lo < hi) { int m = (lo + hi) >> 1; if (batch[m] < g) lo = m + 1; else hi = m; }
    int a = lo;
    lo = 0; hi = NN;
    while (lo < hi) { int m = (lo + hi) >> 1; if (batch[m] < g + 1) lo = m + 1; else hi = m; }
    cnt[g] = lo - a;
  }
}

// ---- K3: dual scatter: dst-records {s|d<<16, x[s]} and src-records {d|sl<<16} ----
__global__ __launch_bounds__(256) void k_bscatter(
    const int* __restrict__ ei, const float* __restrict__ x,
    int* __restrict__ bcur, int* __restrict__ scur,
    uint2* __restrict__ recs, unsigned int* __restrict__ srecs) {
  __shared__ int lhd[NBK]; __shared__ int gbd[NBK];
  __shared__ int lhs[NBS]; __shared__ int gbs[NBS];
  int b = blockIdx.x, tid = threadIdx.x;
  int e0 = b * EPB;
  for (int i = tid; i < NBK; i += 256) lhd[i] = 0;
  for (int i = tid; i < NBS; i += 256) lhs[i] = 0;
  __syncthreads();
  unsigned int meta[8]; float xv[8]; int lofd[8]; int bkd[8]; int lofs[8]; int bks[8];
#pragma unroll
  for (int i = 0; i < 8; ++i) {
    int e = e0 + i * 256 + tid;
    bkd[i] = -1;
    if (e < NE) {
      int s = ei[e], d = ei[NE + e];
      bkd[i] = d >> 8; bks[i] = s >> 7;
      meta[i] = (unsigned int)s | ((unsigned int)d << 16);  // s,d < 65536
      xv[i] = x[s];
      lofd[i] = atomicAdd(&lhd[bkd[i]], 1);
      lofs[i] = atomicAdd(&lhs[bks[i]], 1);
    }
  }
  __syncthreads();
  for (int i = tid; i < NBK; i += 256) gbd[i] = atomicAdd(&bcur[i], lhd[i]);
  for (int i = tid; i < NBS; i += 256) gbs[i] = atomicAdd(&scur[i], lhs[i]);
  __syncthreads();
#pragma unroll
  for (int i = 0; i < 8; ++i) {
    if (bkd[i] >= 0) {
      recs[gbd[bkd[i]] + lofd[i]] = make_uint2(meta[i], asu(xv[i]));
      unsigned int s = meta[i] & 0xFFFFu, d = meta[i] >> 16;
      srecs[gbs[bks[i]] + lofs[i]] = d | ((s & 127u) << 16);
    }
  }
}

// ---- K4: per-dst-bucket fine CSR + per-node ax + dg table + colx scatter ----
__global__ __launch_bounds__(256) void k_csr(
    const uint2* __restrict__ recs, const int* __restrict__ bbase,
    const float* __restrict__ x, const int* __restrict__ batch,
    int* __restrict__ rowp, float2* __restrict__ ax,
    int* __restrict__ colx, uint2* __restrict__ dg) {
  __shared__ int cnt[256];
  __shared__ int sc[256];
  __shared__ float xs[256];
  int b = blockIdx.x, tid = threadIdx.x;
  int eb = bbase[b], ee = bbase[b + 1];
  cnt[tid] = 0;
  xs[tid] = 0.0f;
  __syncthreads();
  for (int e = eb + tid; e < ee; e += 256) {
    uint2 r = recs[e];
    int dl = (r.x >> 16) & 255;
    atomicAdd(&cnt[dl], 1);
    atomicAdd(&xs[dl], asf(r.y));
  }
  __syncthreads();
  sc[tid] = cnt[tid];
  __syncthreads();
  for (int off = 1; off < 256; off <<= 1) {
    int o = (tid >= off) ? sc[tid - off] : 0;
    __syncthreads();
    sc[tid] += o;
    __syncthreads();
  }
  int excl = sc[tid] - cnt[tid];
  int i = b * 256 + tid;
  float dinv = 1.0f / fmaxf((float)cnt[tid], 1.0f);
  if (i < NN) {
    rowp[i] = eb + excl;
    ax[i] = make_float2(xs[tid] * dinv, x[i]);
    dg[i] = make_uint2(asu(dinv), (unsigned int)batch[i]);
  }
  __syncthreads();
  sc[tid] = excl;  // cursor
  __syncthreads();
  for (int e = eb + tid; e < ee; e += 256) {
    uint2 r = recs[e];
    int dl = (r.x >> 16) & 255;
    int s = r.x & 0xFFFF;
    int slot = atomicAdd(&sc[dl], 1);
    colx[eb + slot] = s;
  }
}

// ---- K5 merged: csc (blocks [0,NBS)) + wprep ([NBS,NBS+512)) + axe (rest) ----
// All three depend only on k_csr outputs and are mutually independent.
// csc: per-src-bucket wg rows in LDS; emit TRANSPOSED bf16 wgT3
// wgT3[g'][s]: rows 0..63 = bf16(wg) (hi), 64..127 = bf16(wg - hi) (lo),
// 128..191 = indicator bf16(batch[s]==g ? 1 : 0). Pad cols (s>=NN): all 0.
__global__ __launch_bounds__(256) void k_cscaxewprep(
    const unsigned int* __restrict__ srecs, const int* __restrict__ sbase,
    const uint2* __restrict__ dg, const int* __restrict__ batch,
    unsigned int* __restrict__ wgT3u,
    const int* __restrict__ colx, const float2* __restrict__ ax,
    float2* __restrict__ axe,
    const float* __restrict__ Wl1, const float* __restrict__ Wr1,
    unsigned short* __restrict__ wcat) {
  __shared__ float wgrow[128 * 65];  // [sl][g], pad 65 to break readout conflicts
  __shared__ int sbt[128];
  int bx = blockIdx.x, tid = threadIdx.x;
  if (bx >= NBS) {
    if (bx < NBS + 512) {  // ---- wprep: 512 blocks x 256 = 131072 = 256*512
      int t = (bx - NBS) * 256 + tid;
      int n = t >> 9, k = t & 511;
      float v = (k < 256) ? Wl1[k * 256 + n] : Wr1[(k - 256) * 256 + n];
      wcat[t] = f2bf(v);
    } else {               // ---- axe: edge-ordered (a0,x) gather (L2 table)
      int e = (bx - NBS - 512) * 256 + tid;
      if (e < NE) axe[e] = ax[colx[e]];
    }
    return;
  }
  int b = bx;  // ---- csc
  for (int i = tid; i < 128 * 65; i += 256) wgrow[i] = 0.0f;
  if (tid < 128) {
    int s = b * 128 + tid;
    sbt[tid] = (s < NN) ? batch[s] : -1;
  }
  __syncthreads();
  int eb = sbase[b], ee = sbase[b + 1];
  for (int e = eb + tid; e < ee; e += 256) {
    unsigned int r = srecs[e];
    int d = r & 0xFFFF;
    int sl = (r >> 16) & 127;
    uint2 t = dg[d];  // {deginv bits, g} — 400KB table, L2-resident
    atomicAdd(&wgrow[sl * 65 + t.y], asf(t.x));
  }
  __syncthreads();
  int s0u = b * 64;  // u32 column base (= b*128 bf16 cols / 2)
  int k = tid & 63;
  for (int rr = 0; rr < 16; ++rr) {
    int g = rr * 4 + (tid >> 6);
    float w0 = wgrow[(2 * k) * 65 + g];
    float w1 = wgrow[(2 * k + 1) * 65 + g];
    unsigned short h0 = f2bf(w0), h1v = f2bf(w1);
    unsigned short l0 = f2bf(w0 - bf2f(h0)), l1 = f2bf(w1 - bf2f(h1v));
    wgT3u[(size_t)g * (NNP / 2) + s0u + k] = (unsigned int)h0 | ((unsigned int)h1v << 16);
    wgT3u[(size_t)(64 + g) * (NNP / 2) + s0u + k] = (unsigned int)l0 | ((unsigned int)l1 << 16);
  }
  int bv0 = sbt[2 * k], bv1 = sbt[2 * k + 1];
  for (int rr = 0; rr < 16; ++rr) {
    int g = rr * 4 + (tid >> 6);
    unsigned int u = ((bv0 == g) ? 0x3F80u : 0u) | ((bv1 == g) ? 0x3F800000u : 0u);
    wgT3u[(size_t)(128 + g) * (NNP / 2) + s0u + k] = u;
  }
}

// ---- layer-1 mean-aggregation: stream edge-ordered axe (R7 form, 8/iter) ----
// Also zero-fills aggb pad rows [NN,NNP) (replaces the pad memset dispatch).
__global__ __launch_bounds__(256) void k_agg2(
    const float2* __restrict__ axe, const int* __restrict__ rowp,
    const float* __restrict__ Wl0, const float* __restrict__ b0,
    const float* __restrict__ Wr0, unsigned short* __restrict__ aggb) {
  int wid = threadIdx.x >> 6, lane = threadIdx.x & 63;
  int gw = blockIdx.x * 4 + wid;
  int tw = gridDim.x * 4;
  float wl[4], wr[4], bb[4];
#pragma unroll
  for (int k = 0; k < 4; ++k) {
    wl[k] = Wl0[lane * 4 + k];
    wr[k] = Wr0[lane * 4 + k];
    bb[k] = b0[lane * 4 + k];
  }
  for (int d = gw; d < NNP; d += tw) {
    if (d >= NN) {  // pad row: finite zeros for gemm1's DMA
      *(uint2*)(aggb + (size_t)d * F1 + lane * 4) = make_uint2(0u, 0u);
      continue;
    }
    int beg = rowp[d], end = rowp[d + 1];
    float a[4] = {0.f, 0.f, 0.f, 0.f};
    float c[4] = {0.f, 0.f, 0.f, 0.f};
    int e = beg;
    for (; e + 7 < end; e += 8) {
      float2 v0 = axe[e], v1 = axe[e + 1], v2 = axe[e + 2], v3 = axe[e + 3];
      float2 v4 = axe[e + 4], v5 = axe[e + 5], v6 = axe[e + 6], v7 = axe[e + 7];
#pragma unroll
      for (int k = 0; k < 4; ++k) {
        a[k] += fmaxf(fmaf(v0.x, wl[k], fmaf(v0.y, wr[k], bb[k])), 0.0f);
        c[k] += fmaxf(fmaf(v1.x, wl[k], fmaf(v1.y, wr[k], bb[k])), 0.0f);
        a[k] += fmaxf(fmaf(v2.x, wl[k], fmaf(v2.y, wr[k], bb[k])), 0.0f);
        c[k] += fmaxf(fmaf(v3.x, wl[k], fmaf(v3.y, wr[k], bb[k])), 0.0f);
        a[k] += fmaxf(fmaf(v4.x, wl[k], fmaf(v4.y, wr[k], bb[k])), 0.0f);
        c[k] += fmaxf(fmaf(v5.x, wl[k], fmaf(v5.y, wr[k], bb[k])), 0.0f);
        a[k] += fmaxf(fmaf(v6.x, wl[k], fmaf(v6.y, wr[k], bb[k])), 0.0f);
        c[k] += fmaxf(fmaf(v7.x, wl[k], fmaf(v7.y, wr[k], bb[k])), 0.0f);
      }
    }
    for (; e + 3 < end; e += 4) {
      float2 v0 = axe[e], v1 = axe[e + 1], v2 = axe[e + 2], v3 = axe[e + 3];
#pragma unroll
      for (int k = 0; k < 4; ++k) {
        a[k] += fmaxf(fmaf(v0.x, wl[k], fmaf(v0.y, wr[k], bb[k])), 0.0f);
        c[k] += fmaxf(fmaf(v1.x, wl[k], fmaf(v1.y, wr[k], bb[k])), 0.0f);
        a[k] += fmaxf(fmaf(v2.x, wl[k], fmaf(v2.y, wr[k], bb[k])), 0.0f);
        c[k] += fmaxf(fmaf(v3.x, wl[k], fmaf(v3.y, wr[k], bb[k])), 0.0f);
      }
    }
    for (; e < end; ++e) {
      float2 v0 = axe[e];
#pragma unroll
      for (int k = 0; k < 4; ++k)
        a[k] += fmaxf(fmaf(v0.x, wl[k], fmaf(v0.y, wr[k], bb[k])), 0.0f);
    }
    float dinv = 1.0f / fmaxf((float)(end - beg), 1.0f);
    uint2 o;
    o.x = (unsigned int)f2bf((a[0] + c[0]) * dinv) | ((unsigned int)f2bf((a[1] + c[1]) * dinv) << 16);
    o.y = (unsigned int)f2bf((a[2] + c[2]) * dinv) | ((unsigned int)f2bf((a[3] + c[3]) * dinv) << 16);
    *(uint2*)(aggb + (size_t)d * F1 + lane * 4) = o;
  }
}

// ---- layer 1 GEMM (R7-exact: LDS double-buffer BK=32, reg-staged, fused h0) ----
#define BM 128
#define BN 128
#define BK 32

__global__ __launch_bounds__(256) void k_gemm1(
    const unsigned short* __restrict__ aggb, const float2* __restrict__ ax,
    const unsigned short* __restrict__ wcat,
    const float* __restrict__ Wl0, const float* __restrict__ b0,
    const float* __restrict__ Wr0, const float* __restrict__ b1,
    unsigned short* __restrict__ h1T) {
  __shared__ unsigned short As[2][BM][BK];
  __shared__ unsigned short Bs[2][BN][BK];
  __shared__ float wl0s[256], wr0s[256], b0s[256];
  int bm = blockIdx.x, ct = blockIdx.y;
  int tid = threadIdx.x;
  int wid = tid >> 6, lane = tid & 63;
  int wr = wid >> 1, wc = wid & 1;
  int rc = lane & 15, kh = lane >> 4;
  int r0 = bm * BM;
  int srow = tid >> 1;   // 0..127: one staged row per thread
  int sslot = tid & 1;   // which 32B half of the 64B k-row

  wl0s[tid] = Wl0[tid];
  wr0s[tid] = Wr0[tid];
  b0s[tid] = b0[tid];

  int rA = r0 + srow;
  bool rAok = rA < NN;
  float2 axv = rAok ? ax[rA] : make_float2(0.f, 0.f);

  f32x4 acc[4][4] = {};  // acc[mf][nf]: rows (kh,j) <-> s, col rc <-> f
  int4 ra0, ra1, rb0, rb1;

#define LOAD_A(kt)                                                             \
  do {                                                                         \
    ra0 = make_int4(0, 0, 0, 0); ra1 = make_int4(0, 0, 0, 0);                  \
    if (rAok) {                                                                \
      const int4* s_ = (const int4*)(aggb + (size_t)rA * F1 + (kt) * BK + sslot * 16); \
      ra0 = s_[0]; ra1 = s_[1];                                                \
    }                                                                          \
  } while (0)

#define LOAD_B(kt)                                                             \
  do {                                                                         \
    const int4* t_ = (const int4*)(wcat + (size_t)(ct * BN + srow) * 512 + (kt) * BK + sslot * 16); \
    rb0 = t_[0]; rb1 = t_[1];                                                  \
  } while (0)

// h0[rA][j] = relu(ax.x*Wl0[j] + ax.y*Wr0[j] + b0[j]) — bit-identical to old k_h0
#define COMP_A(kt)                                                             \
  do {                                                                         \
    int j0_ = ((kt) - 8) * BK + sslot * 16;                                    \
    unsigned int w_[8];                                                        \
    _Pragma("unroll") for (int q = 0; q < 8; ++q) {                            \
      int j_ = j0_ + 2 * q;                                                    \
      float f0_ = fmaxf(fmaf(axv.x, wl0s[j_], fmaf(axv.y, wr0s[j_], b0s[j_])), 0.0f); \
      float f1_ = fmaxf(fmaf(axv.x, wl0s[j_ + 1], fmaf(axv.y, wr0s[j_ + 1], b0s[j_ + 1])), 0.0f); \
      w_[q] = (unsigned int)f2bf(f0_) | ((unsigned int)f2bf(f1_) << 16);       \
    }                                                                          \
    ra0 = make_int4(w_[0], w_[1], w_[2], w_[3]);                               \
    ra1 = make_int4(w_[4], w_[5], w_[6], w_[7]);                               \
  } while (0)

// swizzle: 4 16B slots/row, phys = logical ^ ((row>>1)&3) -> 2-way (free) on read
#define WRITE_AB(buf)                                                          \
  do {                                                                         \
    int sw_ = (srow >> 1) & 3;                                                 \
    int ws0_ = (2 * sslot) ^ sw_;                                              \
    int ws1_ = (2 * sslot + 1) ^ sw_;                                          \
    *(int4*)&As[buf][srow][ws0_ * 8] = ra0;                                    \
    *(int4*)&As[buf][srow][ws1_ * 8] = ra1;                                    \
    *(int4*)&Bs[buf][srow][ws0_ * 8] = rb0;                                    \
    *(int4*)&Bs[buf][srow][ws1_ * 8] = rb1;                                    \
  } while (0)

  LOAD_B(0);
  LOAD_A(0);
  WRITE_AB(0);
  __syncthreads();
  int cur = 0;
  for (int kt = 0; kt < 16; ++kt) {
    if (kt < 15) {
      LOAD_B(kt + 1);
      if (kt + 1 < 8) LOAD_A(kt + 1);
    }
    bf16x8 af[4], bfr[4];
#pragma unroll
    for (int mf = 0; mf < 4; ++mf) {
      int row = wr * 64 + mf * 16 + rc;
      int sl = kh ^ ((row >> 1) & 3);
      af[mf] = *(const bf16x8*)&As[cur][row][sl * 8];
    }
#pragma unroll
    for (int nf = 0; nf < 4; ++nf) {
      int row = wc * 64 + nf * 16 + rc;
      int sl = kh ^ ((row >> 1) & 3);
      bfr[nf] = *(const bf16x8*)&Bs[cur][row][sl * 8];
    }
#pragma unroll
    for (int mf = 0; mf < 4; ++mf)
#pragma unroll
      for (int nf = 0; nf < 4; ++nf)
        acc[mf][nf] = __builtin_amdgcn_mfma_f32_16x16x32_bf16(af[mf], bfr[nf], acc[mf][nf], 0, 0, 0);
    if (kt < 15) {
      if (kt + 1 >= 8) COMP_A(kt + 1);
      WRITE_AB(cur ^ 1);
    }
    __syncthreads();
    cur ^= 1;
  }
#undef LOAD_A
#undef LOAD_B
#undef COMP_A
#undef WRITE_AB

  // ---- epilogue: bias+relu, direct h1T[f][s] 8B stores ----
#pragma unroll
  for (int nf = 0; nf < 4; ++nf) {
    int f = ct * BN + wc * 64 + nf * 16 + rc;
    float bias = b1[f];
    size_t frow = (size_t)f * NNP;
#pragma unroll
    for (int mf = 0; mf < 4; ++mf) {
      int s0 = r0 + wr * 64 + mf * 16 + kh * 4;
      f32x4 a = acc[mf][nf];
      unsigned int lo = (unsigned int)f2bf(fmaxf(a[0] + bias, 0.0f)) |
                        ((unsigned int)f2bf(fmaxf(a[1] + bias, 0.0f)) << 16);
      unsigned int hi = (unsigned int)f2bf(fmaxf(a[2] + bias, 0.0f)) |
                        ((unsigned int)f2bf(fmaxf(a[3] + bias, 0.0f)) << 16);
      *(uint2*)(h1T + frow + s0) = make_uint2(lo, hi);
    }
  }
}

// ---- pool contraction: global_load_lds double-buffered MFMA streamer ----
// (R7 structure, unchanged — 189us round verified.)
__global__ __launch_bounds__(256, 2) void k_poolmm(
    const unsigned short* __restrict__ h1T, const unsigned short* __restrict__ wgT3,
    float* __restrict__ zpart) {
  __shared__ unsigned short SM[2][2048 * 8];  // 2 x 32KB: slots 0..1535 = A(192 rows), 1536..2047 = B(64 rows)
  int bid = blockIdx.x;
  int lbid = (bid & 7) * 56 + (bid >> 3);  // XCD-bucket: 4 f-slices of a chunk share an XCD
  int c = lbid >> 2, fs = lbid & 3;
  int tid = threadIdx.x;
  int w = tid >> 6, lane = tid & 63, rc = lane & 15, kh = lane >> 4;
  int kbase = c * PKC;
  int fbase = fs * 64;

  const unsigned short* gsrc[8];
#pragma unroll
  for (int r = 0; r < 8; ++r) {
    int sIdx = r * 256 + tid;
    if (sIdx < 1536) {
      int row = sIdx >> 3, sl = sIdx & 7;
      gsrc[r] = wgT3 + (size_t)row * NNP + kbase + (sl ^ (row & 7)) * 8;
    } else {
      int row = (sIdx - 1536) >> 3, sl = sIdx & 7;
      gsrc[r] = h1T + (size_t)(fbase + row) * NNP + kbase + (sl ^ (row & 7)) * 8;
    }
  }

  f32x4 acc[12] = {};

#define PSTAGE(buf, t)                                                         \
  do {                                                                         \
    _Pragma("unroll") for (int r = 0; r < 8; ++r)                              \
      gload16(gsrc[r] + (t) * 64, &SM[buf][(r * 256 + w * 64) * 8]);           \
  } while (0)

#define PCOMP(buf)                                                             \
  do {                                                                         \
    _Pragma("unroll") for (int ks = 0; ks < 2; ++ks) {                         \
      int brow = w * 16 + rc;                                                  \
      int bsl = (ks * 4 + kh) ^ (brow & 7);                                    \
      bf16x8 bf = *(const bf16x8*)&SM[buf][(1536 + brow * 8 + bsl) * 8];       \
      _Pragma("unroll") for (int mt = 0; mt < 12; ++mt) {                      \
        int arow = mt * 16 + rc;                                               \
        int asl = (ks * 4 + kh) ^ (arow & 7);                                  \
        bf16x8 af = *(const bf16x8*)&SM[buf][(arow * 8 + asl) * 8];            \
        acc[mt] = __builtin_amdgcn_mfma_f32_16x16x32_bf16(af, bf, acc[mt], 0, 0, 0); \
      }                                                                        \
    }                                                                          \
  } while (0)

  PSTAGE(0, 0);
  __syncthreads();
#pragma unroll
  for (int t = 0; t < PSTEPS; ++t) {
    int buf = t & 1;
    if (t + 1 < PSTEPS) PSTAGE(buf ^ 1, t + 1);
    PCOMP(buf);
    __syncthreads();
  }
#undef PSTAGE
#undef PCOMP

  float* zp = zpart + ((size_t)c * ZR2) * F1 + fbase + w * 16 + rc;
#pragma unroll
  for (int mt = 0; mt < 4; ++mt)
#pragma unroll
    for (int r = 0; r < 4; ++r)
      zp[(size_t)(mt * 16 + kh * 4 + r) * F1] = acc[mt][r] + acc[mt + 4][r];
#pragma unroll
  for (int mt = 8; mt < 12; ++mt)
#pragma unroll
    for (int r = 0; r < 4; ++r)
      zp[(size_t)((mt - 8) * 16 + 64 + kh * 4 + r) * F1] = acc[mt][r];
}

// ---- zpart reduction, NON-ATOMIC: one block owns one output row ----
// grid (NG, 2): y==0 -> z[g][:] = sum_c zrow; y==1 -> p1[g][:] = sum_c ind.
// Direct stores (no atomics) -> the z/p1 memset dispatches are removed.
__global__ void k_zred(const float* __restrict__ zpart, float* __restrict__ z,
                       float* __restrict__ p1) {
  int g = blockIdx.x, which = blockIdx.y, t = threadIdx.x;  // 256 threads
  int row = which ? (64 + g) : g;
  float a = 0.0f;
  for (int c = 0; c < PCHUNKS; ++c)
    a += zpart[((size_t)c * ZR2 + row) * F1 + t];
  float* dst = which ? p1 : z;
  dst[g * F1 + t] = a;
}

// ---- final: g = (Z/cnt)@Wl2 + b2 + (P/cnt)@Wr2, then LayerNorm ----
__global__ void k_final(const float* __restrict__ z, const float* __restrict__ p1,
                        const int* __restrict__ cnt,
                        const float* __restrict__ Wl2, const float* __restrict__ b2,
                        const float* __restrict__ Wr2, const float* __restrict__ gamma,
                        const float* __restrict__ beta, float* __restrict__ out) {
  __shared__ float s1[128], s2[128];
  int g = blockIdx.x, j = threadIdx.x;
  float invc = 1.0f / fmaxf((float)cnt[g], 1.0f);
  float acc = 0.0f;
  for (int k = 0; k < 256; ++k) {
    acc += z[g * 256 + k] * Wl2[k * 128 + j] + p1[g * 256 + k] * Wr2[k * 128 + j];
  }
  acc = acc * invc + b2[j];
  s1[j] = acc; s2[j] = acc * acc;
  __syncthreads();
  for (int off = 64; off > 0; off >>= 1) {
    if (j < off) { s1[j] += s1[j + off]; s2[j] += s2[j + off]; }
    __syncthreads();
  }
  float mu = s1[0] / 128.0f;
  float var = s2[0] / 128.0f - mu * mu;
  out[g * 128 + j] = (acc - mu) * rsqrtf(var + 1e-5f) * gamma[j] + beta[j];
}

extern "C" void kernel_launch(void* const* d_in, const int* in_sizes, int n_in,
                              void* d_out, int out_size, void* d_ws, size_t ws_size,
                              hipStream_t stream) {
  const float* x = (const float*)d_in[0];
  const int* ei = (const int*)d_in[1];
  const int* batch = (const int*)d_in[2];
  const float* Wl0 = (const float*)d_in[3];
  const float* b0 = (const float*)d_in[4];
  const float* Wr0 = (const float*)d_in[5];
  const float* Wl1 = (const float*)d_in[6];
  const float* b1 = (const float*)d_in[7];
  const float* Wr1 = (const float*)d_in[8];
  const float* Wl2 = (const float*)d_in[9];
  const float* b2 = (const float*)d_in[10];
  const float* Wr2 = (const float*)d_in[11];
  const float* gamma = (const float*)d_in[12];
  const float* beta = (const float*)d_in[13];
  float* out = (float*)d_out;

  char* p = (char*)d_ws;
  auto alloc = [&](size_t bytes) {
    char* r = p;
    p += (bytes + 511) & ~(size_t)511;
    return r;
  };
  unsigned short* h1T = (unsigned short*)alloc((size_t)F1 * NNP * 2);    // 25.7MB transposed h1
  unsigned short* aggb = (unsigned short*)alloc((size_t)NNP * F1 * 2);   // padded to NNP rows; hosts recs+srecs early
  int* colx = (int*)alloc((size_t)NE * 4);                               // 3.2MB
  float2* axe = (float2*)alloc((size_t)NE * 8);                          // 6.4MB edge-ordered (a0,x)
  int* rowp = (int*)alloc((size_t)(NN + 1) * 4);
  float2* ax = (float2*)alloc((size_t)NN * 8);
  uint2* dg = (uint2*)alloc((size_t)NN * 8);
  int* cnt = (int*)alloc((size_t)NG * 4);
  float* z = (float*)alloc((size_t)NG * F1 * 4);
  float* p1 = (float*)alloc((size_t)NG * F1 * 4);
  unsigned short* wcat = (unsigned short*)alloc((size_t)256 * 512 * 2);
  int* btot = (int*)alloc((size_t)(NBK + NBS) * 4);                      // single zeroed region
  int* bbase = (int*)alloc((size_t)(NBK + 1) * 4);
  int* bcur = (int*)alloc((size_t)NBK * 4);
  int* sbase = (int*)alloc((size_t)(NBS + 1) * 4);
  int* scur = (int*)alloc((size_t)NBS * 4);
  unsigned short* wgT3 = (unsigned short*)alloc((size_t)192 * NNP * 2);  // 19.3MB hi/lo/ind bf16
  float* zpart = (float*)alloc((size_t)PCHUNKS * ZR2 * F1 * 4);          // 14.7MB split-K partials
  int* btot_d = btot;
  int* btot_s = btot + NBK;
  // Aliasing inside aggb: recs (uint2, 6.4MB @0), srecs (uint, 3.2MB @6.4MB).
  // recs dead after k_csr; srecs dead after the merged csc — both before
  // k_agg2 writes aggb. aggb pad rows [NN,NNP) are zero-filled by k_agg2.
  uint2* recs = (uint2*)aggb;
  unsigned int* srecs = (unsigned int*)(aggb + (size_t)NE * 4);

  hipMemsetAsync(btot, 0, (size_t)(NBK + NBS) * 4, stream);  // the ONLY memset

  k_bhist<<<256, 256, 0, stream>>>(ei, btot_d, btot_s);
  k_bscan<<<1, 512, 0, stream>>>(btot_d, btot_s, bbase, bcur, sbase, scur, rowp, batch, cnt);
  k_bscatter<<<SCB, 256, 0, stream>>>(ei, x, bcur, scur, recs, srecs);
  k_csr<<<NBK, 256, 0, stream>>>(recs, bbase, x, batch, rowp, ax, colx, dg);
  k_cscaxewprep<<<NBS + 512 + (NE + 255) / 256, 256, 0, stream>>>(
      srecs, sbase, dg, batch, (unsigned int*)wgT3, colx, ax, axe, Wl1, Wr1, wcat);
  k_agg2<<<2048, 256, 0, stream>>>(axe, rowp, Wl0, b0, Wr0, aggb);
  dim3 gg(392, 2);
  k_gemm1<<<gg, 256, 0, stream>>>(aggb, ax, wcat, Wl0, b0, Wr0, b1, h1T);
  k_poolmm<<<4 * PCHUNKS, 256, 0, stream>>>(h1T, wgT3, zpart);
  dim3 zg(NG, 2);
  k_zred<<<zg, 256, 0, stream>>>(zpart, z, p1);
  k_final<<<NG, 128, 0, stream>>>(z, p1, cnt, Wl2, b2, Wr2, gamma, beta, out);
}